// Round 1
// baseline (594.944 us; speedup 1.0000x reference)
//
#include <hip/hip_runtime.h>
#include <stdint.h>

// GatedLSTM — single persistent-grid fused kernel.
// Roles: blocks 0..63 = char LSTM (13 steps, atomic barrier per step, weights in regs)
//        blocks 64..191 = gate g (bx 64) + mix (cte@c2) + word layer0 (weights preloaded in regs)
//        blocks 192..319 = word layer1 (weights preloaded in regs)
//        all 320 blocks  = decoder (50000x512 matvec), with dec_W LLC prefetch during waits.
// Sync: device-scope atomic counters in ws (byte 16384), zeroed via hipMemsetAsync per launch.
// ws float layout: 0 h1[2][256] | 512 h2[2][256] | 1024 c1[256] | 1280 c2[256]
//                  1536 xcw[512] | 2048 hw1[512] | 2560 hw2[512] | 3072 g | 4096 int cnt[...]

#define SCOPE_AGT __HIP_MEMORY_SCOPE_AGENT

static __device__ __forceinline__ float dot4(float4 w, const float* p){
    return w.x*p[0] + w.y*p[1] + w.z*p[2] + w.w*p[3];
}
static __device__ __forceinline__ float dot44(float4 a, float4 b){
    return a.x*b.x + a.y*b.y + a.z*b.z + a.w*b.w;
}
static __device__ __forceinline__ float sigf(float x){ return 1.0f / (1.0f + __expf(-x)); }
static __device__ __forceinline__ float tanhf_(float x){
    x = fminf(fmaxf(x, -15.0f), 15.0f);
    float e = __expf(2.0f * x);
    return (e - 1.0f) / (e + 1.0f);
}
static __device__ __forceinline__ void arrive(int* c){
    __hip_atomic_fetch_add(c, 1, __ATOMIC_RELEASE, SCOPE_AGT);
}
static __device__ __forceinline__ void wait_ge(int* c, int tgt){
    while (__hip_atomic_load(c, __ATOMIC_ACQUIRE, SCOPE_AGT) < tgt)
        __builtin_amdgcn_s_sleep(2);
}

// Warm LLC with this wave's own decoder rows while waiting on a flag.
// Scalar touch every 32B covers every 128B line of the 2KB row.
static __device__ __forceinline__ void dec_prefetch(const float* __restrict__ dec_W,
                                                    int* c, int tgt, int wid, int lane){
    float pf = 0.f;
    int stop = 0, it = 0;
    for (int r = wid; r < 50000; r += 1280, ++it){
        if ((it & 7) == 0){
            if (lane == 0) stop = (__hip_atomic_load(c, __ATOMIC_RELAXED, SCOPE_AGT) >= tgt);
            stop = __shfl(stop, 0, 64);
            if (stop) break;
        }
        pf += dec_W[(size_t)r * 512 + lane * 8];
    }
    asm volatile("" :: "v"(pf));   // keep loads alive
}

__global__ __launch_bounds__(256, 2) void k_fused(
    const int* __restrict__ x_word, const int* __restrict__ x_char,
    const float* __restrict__ hwh, const float* __restrict__ hwc,
    const float* __restrict__ hch, const float* __restrict__ hcc,
    const float* __restrict__ word_emb,
    const float* __restrict__ wWih, const float* __restrict__ wWhh,
    const float* __restrict__ wbih, const float* __restrict__ wbhh,
    const float* __restrict__ dec_W, const float* __restrict__ dec_b,
    const float* __restrict__ char_emb,
    const float* __restrict__ cWih, const float* __restrict__ cWhh,
    const float* __restrict__ cbih, const float* __restrict__ cbhh,
    const float* __restrict__ cte,
    const float* __restrict__ g_w, const float* __restrict__ g_b,
    float* __restrict__ ws, float* __restrict__ out)
{
    const int tid  = threadIdx.x;
    const int bx   = blockIdx.x;
    const int lane = tid & 63;
    const int wv   = tid >> 6;
    int* cnt = (int*)(ws + 4096);   // [0]=char barrier, [1]=mix, [2]=w0 done, [3]=w1 done

    if (bx < 64){
        // ================= char LSTM role =================
        __shared__ float sH1[256], sH2[256], sE[256], sg1[16], sg2[16];
        float* h1b = ws;
        float* h2b = ws + 512;
        float* c1  = ws + 1024;
        float* c2  = ws + 1280;

        const int rg = tid >> 4, lane16 = tid & 15;
        const int gate = rg & 3, uu = rg >> 2;
        const int u = (bx << 2) + uu;
        const int row = (gate << 8) + u, row2 = 1024 + row;

        // preload this thread's char weights (16 float4 = 64 VGPRs)
        float4 w1i[4], w1h[4], w2i[4], w2h[4];
        {
            const float4* p1i = (const float4*)(cWih + (size_t)row  * 256) + lane16 * 4;
            const float4* p1h = (const float4*)(cWhh + (size_t)row  * 256) + lane16 * 4;
            const float4* p2i = (const float4*)(cWih + (size_t)row2 * 256) + lane16 * 4;
            const float4* p2h = (const float4*)(cWhh + (size_t)row2 * 256) + lane16 * 4;
            #pragma unroll
            for (int j = 0; j < 4; ++j){ w1i[j]=p1i[j]; w1h[j]=p1h[j]; w2i[j]=p2i[j]; w2h[j]=p2h[j]; }
        }
        const float b1 = cbih[row]  + cbhh[row];
        const float b2 = cbih[row2] + cbhh[row2];

        for (int t = 0; t <= 12; ++t){
            sH1[tid] = (t == 0) ? hch[tid] : h1b[(t & 1)*256 + tid];
            if (t >= 1) sH2[tid] = (t == 1) ? hch[256 + tid] : h2b[((t-1) & 1)*256 + tid];
            if (t < 12) sE[tid] = char_emb[x_char[t]*256 + tid];
            __syncthreads();

            float a1 = 0.f, a2 = 0.f;
            if (t < 12){
                const float* xp = sE  + lane16*16;
                const float* hp = sH1 + lane16*16;
                #pragma unroll
                for (int j = 0; j < 4; ++j) a1 += dot4(w1i[j], xp + 4*j) + dot4(w1h[j], hp + 4*j);
            }
            if (t >= 1){
                const float* xp = sH1 + lane16*16;
                const float* hp = sH2 + lane16*16;
                #pragma unroll
                for (int j = 0; j < 4; ++j) a2 += dot4(w2i[j], xp + 4*j) + dot4(w2h[j], hp + 4*j);
            }
            #pragma unroll
            for (int m = 8; m >= 1; m >>= 1){
                a1 += __shfl_xor(a1, m, 64);
                a2 += __shfl_xor(a2, m, 64);
            }
            if (lane16 == 0){
                if (t < 12) sg1[rg] = a1 + b1;
                if (t >= 1) sg2[rg] = a2 + b2;
            }
            __syncthreads();

            if (tid < 4){
                if (t < 12){
                    int uh = (bx << 2) + tid;
                    float gi = sigf(sg1[tid*4+0]);
                    float gf = sigf(sg1[tid*4+1]);
                    float gg = tanhf_(sg1[tid*4+2]);
                    float go = sigf(sg1[tid*4+3]);
                    float cp = (t == 0) ? hcc[uh] : c1[uh];
                    float c = gf * cp + gi * gg;
                    c1[uh] = c;
                    h1b[((t+1) & 1)*256 + uh] = go * tanhf_(c);
                }
            } else if (tid < 8){
                if (t >= 1){
                    int q = tid - 4;
                    int uh = (bx << 2) + q;
                    float gi = sigf(sg2[q*4+0]);
                    float gf = sigf(sg2[q*4+1]);
                    float gg = tanhf_(sg2[q*4+2]);
                    float go = sigf(sg2[q*4+3]);
                    float cp = (t == 1) ? hcc[256 + uh] : c2[uh];
                    float c = gf * cp + gi * gg;
                    c2[uh] = c;
                    h2b[(t & 1)*256 + uh] = go * tanhf_(c);
                }
            }
            __syncthreads();
            // 64-block barrier: release own writes, acquire others'
            if (tid == 0){
                arrive(&cnt[0]);
                if (t < 12) wait_ge(&cnt[0], 64*(t+1));
            }
            __syncthreads();
        }
        // final char states (own-block data only)
        if (tid < 4){
            int uh = (bx << 2) + tid;
            out[52048 + uh]       = h1b[uh];        // h_char_h layer0 (buffer 0)
            out[52048 + 256 + uh] = h2b[uh];        // h_char_h layer1 (buffer 0)
            out[52560 + uh]       = c1[uh];         // h_char_c layer0
            out[52560 + 256 + uh] = c2[uh];         // h_char_c layer1
        }
        dec_prefetch(dec_W, &cnt[3], 128, (bx << 2) + wv, lane);

    } else if (bx < 192){
        // ================= gate + mix + word layer 0 =================
        const int vw = ((bx - 64) << 2) + wv;        // hidden unit 0..511
        float4 wi0[4], wi1[4], wh0[4], wh1[4]; float bs[4];
        #pragma unroll
        for (int gq = 0; gq < 4; ++gq){
            const size_t rf = (size_t)((gq << 9) + vw);
            const float4* pi = (const float4*)(wWih + rf*512) + lane*2;
            const float4* ph = (const float4*)(wWhh + rf*512) + lane*2;
            wi0[gq] = pi[0]; wi1[gq] = pi[1];
            wh0[gq] = ph[0]; wh1[gq] = ph[1];
            bs[gq] = wbih[rf] + wbhh[rf];
        }
        const float4* hv = (const float4*)(hwh) + lane*2;
        const float4 hva = hv[0], hvb = hv[1];
        const size_t wbase = (size_t)x_word[0] * 512;
        const float4* wep = (const float4*)(word_emb + wbase) + lane*2;
        const float4 wea = wep[0], web = wep[1];

        if (bx == 64){
            // scalar gate g (independent of char phase)
            __shared__ float sw[4];
            float p = g_w[2*tid]   * word_emb[wbase + 2*tid]
                    + g_w[2*tid+1] * word_emb[wbase + 2*tid+1];
            #pragma unroll
            for (int m = 32; m >= 1; m >>= 1) p += __shfl_xor(p, m, 64);
            if (lane == 0) sw[wv] = p;
            __syncthreads();
            if (tid == 0) ws[3072] = fmaxf(sw[0]+sw[1]+sw[2]+sw[3] + g_b[0], 0.0f);
        }

        if (tid == 0) wait_ge(&cnt[0], 64*13);       // char done
        __syncthreads();

        // mix: xcw[vw] = cte[vw,:] . c2
        {
            float4 cv  = ((const float4*)(cte + (size_t)vw*256))[lane];
            float4 c2v = ((const float4*)(ws + 1280))[lane];
            float acc = dot44(cv, c2v);
            #pragma unroll
            for (int m = 32; m >= 1; m >>= 1) acc += __shfl_xor(acc, m, 64);
            if (lane == 0) ws[1536 + vw] = acc;
        }
        __syncthreads();
        if (tid == 0){ arrive(&cnt[1]); wait_ge(&cnt[1], 128); }
        __syncthreads();

        // word layer 0 (one unit per wave; rows u, 512+u, 1024+u, 1536+u)
        {
            const float g  = ws[3072];
            const float og = 1.0f - g;
            const float4* xc = (const float4*)(ws + 1536) + lane*2;
            const float4 x0 = xc[0], x1 = xc[1];
            float4 xa, xb;
            xa.x = og*wea.x + g*x0.x; xa.y = og*wea.y + g*x0.y;
            xa.z = og*wea.z + g*x0.z; xa.w = og*wea.w + g*x0.w;
            xb.x = og*web.x + g*x1.x; xb.y = og*web.y + g*x1.y;
            xb.z = og*web.z + g*x1.z; xb.w = og*web.w + g*x1.w;
            float ac[4];
            #pragma unroll
            for (int gq = 0; gq < 4; ++gq){
                float a = dot44(wi0[gq], xa) + dot44(wi1[gq], xb)
                        + dot44(wh0[gq], hva) + dot44(wh1[gq], hvb);
                #pragma unroll
                for (int m = 32; m >= 1; m >>= 1) a += __shfl_xor(a, m, 64);
                ac[gq] = a;
            }
            if (lane == 0){
                float gi = sigf(ac[0] + bs[0]);
                float gf = sigf(ac[1] + bs[1]);
                float gg = tanhf_(ac[2] + bs[2]);
                float go = sigf(ac[3] + bs[3]);
                float c = gf * hwc[vw] + gi * gg;
                float h = go * tanhf_(c);
                ws[2048 + vw]  = h;
                out[50000 + vw] = h;
                out[51024 + vw] = c;
            }
        }
        __syncthreads();
        if (tid == 0) arrive(&cnt[2]);
        dec_prefetch(dec_W, &cnt[3], 128, (bx << 2) + wv, lane);

    } else {
        // ================= word layer 1 =================
        const int vw = ((bx - 192) << 2) + wv;       // hidden unit 0..511
        float4 wi0[4], wi1[4], wh0[4], wh1[4]; float bs[4];
        #pragma unroll
        for (int gq = 0; gq < 4; ++gq){
            const size_t rf = (size_t)(2048 + (gq << 9) + vw);
            const float4* pi = (const float4*)(wWih + rf*512) + lane*2;
            const float4* ph = (const float4*)(wWhh + rf*512) + lane*2;
            wi0[gq] = pi[0]; wi1[gq] = pi[1];
            wh0[gq] = ph[0]; wh1[gq] = ph[1];
            bs[gq] = wbih[rf] + wbhh[rf];
        }
        const float4* hv = (const float4*)(hwh + 512) + lane*2;
        const float4 hva = hv[0], hvb = hv[1];

        // hide part of the dec_W HBM read under the char/mix/w0 phases
        dec_prefetch(dec_W, &cnt[2], 128, (bx << 2) + wv, lane);

        if (tid == 0) wait_ge(&cnt[2], 128);         // layer0 done
        __syncthreads();
        {
            const float4* xc = (const float4*)(ws + 2048) + lane*2;
            const float4 xa = xc[0], xb = xc[1];
            float ac[4];
            #pragma unroll
            for (int gq = 0; gq < 4; ++gq){
                float a = dot44(wi0[gq], xa) + dot44(wi1[gq], xb)
                        + dot44(wh0[gq], hva) + dot44(wh1[gq], hvb);
                #pragma unroll
                for (int m = 32; m >= 1; m >>= 1) a += __shfl_xor(a, m, 64);
                ac[gq] = a;
            }
            if (lane == 0){
                float gi = sigf(ac[0] + bs[0]);
                float gf = sigf(ac[1] + bs[1]);
                float gg = tanhf_(ac[2] + bs[2]);
                float go = sigf(ac[3] + bs[3]);
                float c = gf * hwc[512 + vw] + gi * gg;
                float h = go * tanhf_(c);
                ws[2560 + vw]        = h;
                out[50000 + 512 + vw] = h;
                out[51024 + 512 + vw] = c;
            }
        }
        __syncthreads();
        if (tid == 0) arrive(&cnt[3]);
    }

    // ================= decoder (all 320 blocks, 1280 waves) =================
    if (tid == 0) wait_ge(&cnt[3], 128);
    __syncthreads();
    {
        const float4* hp = (const float4*)(ws + 2560) + lane*2;
        const float4 ha = hp[0], hb = hp[1];
        const int wid = (bx << 2) + wv;
        for (int r = wid; r < 50000; r += 1280){
            const float4* wp = (const float4*)(dec_W + (size_t)r*512) + lane*2;
            float acc = dot44(wp[0], ha) + dot44(wp[1], hb);
            #pragma unroll
            for (int m = 32; m >= 1; m >>= 1) acc += __shfl_xor(acc, m, 64);
            if (lane == 0) out[r] = acc + dec_b[r];
        }
    }
}

extern "C" void kernel_launch(void* const* d_in, const int* in_sizes, int n_in,
                              void* d_out, int out_size, void* d_ws, size_t ws_size,
                              hipStream_t stream)
{
    const int*   x_word   = (const int*)d_in[0];
    const int*   x_char   = (const int*)d_in[1];
    const float* hwh      = (const float*)d_in[2];
    const float* hwc      = (const float*)d_in[3];
    const float* hch      = (const float*)d_in[4];
    const float* hcc      = (const float*)d_in[5];
    const float* word_emb = (const float*)d_in[6];
    const float* wWih     = (const float*)d_in[7];
    const float* wWhh     = (const float*)d_in[8];
    const float* wbih     = (const float*)d_in[9];
    const float* wbhh     = (const float*)d_in[10];
    const float* dec_W    = (const float*)d_in[11];
    const float* dec_b    = (const float*)d_in[12];
    const float* char_emb = (const float*)d_in[13];
    const float* cWih     = (const float*)d_in[14];
    const float* cWhh     = (const float*)d_in[15];
    const float* cbih     = (const float*)d_in[16];
    const float* cbhh     = (const float*)d_in[17];
    const float* cte      = (const float*)d_in[18];
    const float* g_w      = (const float*)d_in[19];
    const float* g_b      = (const float*)d_in[20];

    float* ws  = (float*)d_ws;
    float* out = (float*)d_out;

    // zero the sync counters (ws byte offset 16384)
    hipMemsetAsync((void*)((char*)d_ws + 16384), 0, 64, stream);

    hipLaunchKernelGGL(k_fused, dim3(320), dim3(256), 0, stream,
        x_word, x_char, hwh, hwc, hch, hcc, word_emb,
        wWih, wWhh, wbih, wbhh, dec_W, dec_b,
        char_emb, cWih, cWhh, cbih, cbhh, cte, g_w, g_b,
        ws, out);
}

// Round 2
// 359.149 us; speedup vs baseline: 1.6565x; 1.6565x over previous
//
#include <hip/hip_runtime.h>
#include <stdint.h>

// GatedLSTM — single persistent-grid fused kernel, round 2.
// Same role structure as round 1, but ALL cross-block sync/data uses RELAXED
// agent-scope atomics (sc1: bypass non-coherent L2, no inv/writeback storms).
// Writers: sc1 stores -> __syncthreads (drains vmcnt) -> relaxed fetch_add.
// Readers: relaxed poll -> __syncthreads -> sc1 loads into LDS.
// Cell states live in registers (block-exclusive). dec_W prefetched into LLC
// by blocks 64..319 (stride-1024 full coverage, 8 loads in flight).
//
// ws float layout: 0 h1[2][256] | 512 h2[2][256] | 1280 c2[256] (published @t==12)
//                  1536 xcw[512] | 2048 hw1[512] | 2560 hw2[512] | 3072 g
//                  4096 int cnt[4]  (byte 16384; memset per launch)

#define SCOPE_AGT __HIP_MEMORY_SCOPE_AGENT

static __device__ __forceinline__ float dot4(float4 w, const float* p){
    return w.x*p[0] + w.y*p[1] + w.z*p[2] + w.w*p[3];
}
static __device__ __forceinline__ float dot44(float4 a, float4 b){
    return a.x*b.x + a.y*b.y + a.z*b.z + a.w*b.w;
}
static __device__ __forceinline__ float sigf(float x){ return 1.0f / (1.0f + __expf(-x)); }
static __device__ __forceinline__ float tanhf_(float x){
    x = fminf(fmaxf(x, -15.0f), 15.0f);
    float e = __expf(2.0f * x);
    return (e - 1.0f) / (e + 1.0f);
}

// sc1 accessors: agent-scope relaxed atomics bypass the per-XCD L2 (coherence
// point = LLC). No cache maintenance instructions are emitted.
static __device__ __forceinline__ float gload(const float* p){
    return __hip_atomic_load(p, __ATOMIC_RELAXED, SCOPE_AGT);
}
static __device__ __forceinline__ void gstore(float* p, float v){
    __hip_atomic_store(p, v, __ATOMIC_RELAXED, SCOPE_AGT);
}
static __device__ __forceinline__ void bar_add(int* c){
    __hip_atomic_fetch_add(c, 1, __ATOMIC_RELAXED, SCOPE_AGT);
}
static __device__ __forceinline__ void bar_wait(int* c, int tgt){
    while (__hip_atomic_load(c, __ATOMIC_RELAXED, SCOPE_AGT) < tgt)
        __builtin_amdgcn_s_sleep(1);
}

// Warm LLC with decoder rows while waiting on a flag; 8 independent chains.
static __device__ __forceinline__ void dec_prefetch(const float* __restrict__ dec_W,
        int* c, int tgt, int start, int stride, int lane){
    float acc[8] = {0.f,0.f,0.f,0.f,0.f,0.f,0.f,0.f};
    int r = start, stop = 0;
    while (r < 50000){
        if (lane == 0) stop = (__hip_atomic_load(c, __ATOMIC_RELAXED, SCOPE_AGT) >= tgt);
        stop = __shfl(stop, 0, 64);
        if (stop) break;
        #pragma unroll
        for (int k = 0; k < 8; ++k){
            int rr = r + k * stride;
            if (rr < 50000) acc[k] += dec_W[(size_t)rr * 512 + lane * 8];
        }
        r += 8 * stride;
    }
    float s = acc[0]+acc[1]+acc[2]+acc[3]+acc[4]+acc[5]+acc[6]+acc[7];
    asm volatile("" :: "v"(s));   // keep loads alive
}

__global__ __launch_bounds__(256, 2) void k_fused(
    const int* __restrict__ x_word, const int* __restrict__ x_char,
    const float* __restrict__ hwh, const float* __restrict__ hwc,
    const float* __restrict__ hch, const float* __restrict__ hcc,
    const float* __restrict__ word_emb,
    const float* __restrict__ wWih, const float* __restrict__ wWhh,
    const float* __restrict__ wbih, const float* __restrict__ wbhh,
    const float* __restrict__ dec_W, const float* __restrict__ dec_b,
    const float* __restrict__ char_emb,
    const float* __restrict__ cWih, const float* __restrict__ cWhh,
    const float* __restrict__ cbih, const float* __restrict__ cbhh,
    const float* __restrict__ cte,
    const float* __restrict__ g_w, const float* __restrict__ g_b,
    float* __restrict__ ws, float* __restrict__ out)
{
    const int tid  = threadIdx.x;
    const int bx   = blockIdx.x;
    const int lane = tid & 63;
    const int wv   = tid >> 6;
    int* cnt = (int*)(ws + 4096);   // [0]=char steps, [1]=mix, [2]=w0, [3]=w1

    if (bx < 64){
        // ================= char LSTM (13 steps, reg-resident weights & cells) =================
        __shared__ float sH1[256], sH2[256], sE[256], sg1[16], sg2[16];
        float* h1b = ws;
        float* h2b = ws + 512;

        const int rg = tid >> 4, lane16 = tid & 15;
        const int gate = rg & 3, uu = rg >> 2;
        const int u = (bx << 2) + uu;
        const int row = (gate << 8) + u, row2 = 1024 + row;

        float4 w1i[4], w1h[4], w2i[4], w2h[4];
        {
            const float4* p1i = (const float4*)(cWih + (size_t)row  * 256) + lane16 * 4;
            const float4* p1h = (const float4*)(cWhh + (size_t)row  * 256) + lane16 * 4;
            const float4* p2i = (const float4*)(cWih + (size_t)row2 * 256) + lane16 * 4;
            const float4* p2h = (const float4*)(cWhh + (size_t)row2 * 256) + lane16 * 4;
            #pragma unroll
            for (int j = 0; j < 4; ++j){ w1i[j]=p1i[j]; w1h[j]=p1h[j]; w2i[j]=p2i[j]; w2h[j]=p2h[j]; }
        }
        const float b1 = cbih[row]  + cbhh[row];
        const float b2 = cbih[row2] + cbhh[row2];

        // block-exclusive cell states in registers
        float c1r = 0.f, c2r = 0.f, h1fin = 0.f, h2fin = 0.f;
        if (tid < 4)      c1r = hcc[(bx<<2) + tid];
        else if (tid < 8) c2r = hcc[256 + (bx<<2) + (tid-4)];

        for (int t = 0; t <= 12; ++t){
            sH1[tid] = (t == 0) ? hch[tid] : gload(h1b + (t & 1)*256 + tid);
            if (t >= 1) sH2[tid] = (t == 1) ? hch[256 + tid]
                                            : gload(h2b + ((t-1) & 1)*256 + tid);
            if (t < 12) sE[tid] = char_emb[x_char[t]*256 + tid];
            __syncthreads();

            float a1 = 0.f, a2 = 0.f;
            if (t < 12){
                const float* xp = sE  + lane16*16;
                const float* hp = sH1 + lane16*16;
                #pragma unroll
                for (int j = 0; j < 4; ++j) a1 += dot4(w1i[j], xp + 4*j) + dot4(w1h[j], hp + 4*j);
            }
            if (t >= 1){
                const float* xp = sH1 + lane16*16;
                const float* hp = sH2 + lane16*16;
                #pragma unroll
                for (int j = 0; j < 4; ++j) a2 += dot4(w2i[j], xp + 4*j) + dot4(w2h[j], hp + 4*j);
            }
            #pragma unroll
            for (int m = 8; m >= 1; m >>= 1){
                a1 += __shfl_xor(a1, m, 64);
                a2 += __shfl_xor(a2, m, 64);
            }
            if (lane16 == 0){
                if (t < 12) sg1[rg] = a1 + b1;
                if (t >= 1) sg2[rg] = a2 + b2;
            }
            __syncthreads();

            if (tid < 4){
                if (t < 12){
                    int uh = (bx << 2) + tid;
                    float gi = sigf(sg1[tid*4+0]);
                    float gf = sigf(sg1[tid*4+1]);
                    float gg = tanhf_(sg1[tid*4+2]);
                    float go = sigf(sg1[tid*4+3]);
                    float c = gf * c1r + gi * gg;
                    c1r = c;
                    float h = go * tanhf_(c);
                    h1fin = h;
                    gstore(h1b + ((t+1) & 1)*256 + uh, h);
                }
            } else if (tid < 8){
                if (t >= 1){
                    int q = tid - 4;
                    int uh = (bx << 2) + q;
                    float gi = sigf(sg2[q*4+0]);
                    float gf = sigf(sg2[q*4+1]);
                    float gg = tanhf_(sg2[q*4+2]);
                    float go = sigf(sg2[q*4+3]);
                    float c = gf * c2r + gi * gg;
                    c2r = c;
                    float h = go * tanhf_(c);
                    h2fin = h;
                    if (t < 12) gstore(h2b + (t & 1)*256 + uh, h);
                    else        gstore(ws + 1280 + uh, c);   // publish final c2 for mix
                }
            }
            __syncthreads();   // drains storers' vmcnt before the arrive
            if (tid == 0){
                bar_add(&cnt[0]);
                if (t < 12) bar_wait(&cnt[0], 64*(t+1));
            }
            __syncthreads();
        }
        // final char states from registers (own-block data only)
        if (tid < 4){
            int uh = (bx << 2) + tid;
            out[52048 + uh] = h1fin;   // h_char_h layer0 (t==11)
            out[52560 + uh] = c1r;     // h_char_c layer0
        } else if (tid < 8){
            int uh = (bx << 2) + (tid - 4);
            out[52048 + 256 + uh] = h2fin;  // h_char_h layer1 (t==12)
            out[52560 + 256 + uh] = c2r;    // h_char_c layer1
        }
        dec_prefetch(dec_W, &cnt[3], 128, (bx << 2) + wv, 1280, lane);

    } else if (bx < 192){
        // ================= gate + mix + word layer 0 =================
        __shared__ float sC2[256];
        __shared__ float sXCW[512];
        __shared__ float sMisc[8];
        const int vw = ((bx - 64) << 2) + wv;        // hidden unit 0..511
        float4 wi0[4], wi1[4], wh0[4], wh1[4]; float bs[4];
        #pragma unroll
        for (int gq = 0; gq < 4; ++gq){
            const size_t rf = (size_t)((gq << 9) + vw);
            const float4* pi = (const float4*)(wWih + rf*512) + lane*2;
            const float4* ph = (const float4*)(wWhh + rf*512) + lane*2;
            wi0[gq] = pi[0]; wi1[gq] = pi[1];
            wh0[gq] = ph[0]; wh1[gq] = ph[1];
            bs[gq] = wbih[rf] + wbhh[rf];
        }
        const float4* hv = (const float4*)(hwh) + lane*2;
        const float4 hva = hv[0], hvb = hv[1];
        const size_t wbase = (size_t)x_word[0] * 512;
        const float4* wep = (const float4*)(word_emb + wbase) + lane*2;
        const float4 wea = wep[0], web = wep[1];

        if (bx == 64){
            float p = g_w[2*tid]   * word_emb[wbase + 2*tid]
                    + g_w[2*tid+1] * word_emb[wbase + 2*tid+1];
            #pragma unroll
            for (int m = 32; m >= 1; m >>= 1) p += __shfl_xor(p, m, 64);
            if (lane == 0) sMisc[wv] = p;
            __syncthreads();
            if (tid == 0)
                gstore(ws + 3072, fmaxf(sMisc[0]+sMisc[1]+sMisc[2]+sMisc[3] + g_b[0], 0.0f));
        }

        // prefetch this role's share of dec_W while the char phase runs
        dec_prefetch(dec_W, &cnt[0], 64*13, ((bx - 64) << 2) + wv, 1024, lane);

        if (tid == 0) bar_wait(&cnt[0], 64*13);      // char done (c2 published)
        __syncthreads();
        sC2[tid] = gload(ws + 1280 + tid);
        __syncthreads();

        // mix: xcw[vw] = cte[vw,:] . c2
        {
            float4 cv  = ((const float4*)(cte + (size_t)vw*256))[lane];
            float4 c2v = ((const float4*)sC2)[lane];
            float acc = dot44(cv, c2v);
            #pragma unroll
            for (int m = 32; m >= 1; m >>= 1) acc += __shfl_xor(acc, m, 64);
            if (lane == 0) gstore(ws + 1536 + vw, acc);
        }
        __syncthreads();
        if (tid == 0){ bar_add(&cnt[1]); bar_wait(&cnt[1], 128); }
        __syncthreads();
        sXCW[tid]       = gload(ws + 1536 + tid);
        sXCW[256 + tid] = gload(ws + 1536 + 256 + tid);
        if (tid == 0) sMisc[4] = gload(ws + 3072);
        __syncthreads();

        // word layer 0 (one unit per wave)
        {
            const float g  = sMisc[4];
            const float og = 1.0f - g;
            const float4 x0 = ((const float4*)sXCW)[lane*2];
            const float4 x1 = ((const float4*)sXCW)[lane*2 + 1];
            float4 xa, xb;
            xa.x = og*wea.x + g*x0.x; xa.y = og*wea.y + g*x0.y;
            xa.z = og*wea.z + g*x0.z; xa.w = og*wea.w + g*x0.w;
            xb.x = og*web.x + g*x1.x; xb.y = og*web.y + g*x1.y;
            xb.z = og*web.z + g*x1.z; xb.w = og*web.w + g*x1.w;
            float ac[4];
            #pragma unroll
            for (int gq = 0; gq < 4; ++gq){
                float a = dot44(wi0[gq], xa) + dot44(wi1[gq], xb)
                        + dot44(wh0[gq], hva) + dot44(wh1[gq], hvb);
                #pragma unroll
                for (int m = 32; m >= 1; m >>= 1) a += __shfl_xor(a, m, 64);
                ac[gq] = a;
            }
            if (lane == 0){
                float gi = sigf(ac[0] + bs[0]);
                float gf = sigf(ac[1] + bs[1]);
                float gg = tanhf_(ac[2] + bs[2]);
                float go = sigf(ac[3] + bs[3]);
                float c = gf * hwc[vw] + gi * gg;
                float h = go * tanhf_(c);
                gstore(ws + 2048 + vw, h);
                out[50000 + vw] = h;
                out[51024 + vw] = c;
            }
        }
        __syncthreads();
        if (tid == 0) bar_add(&cnt[2]);
        dec_prefetch(dec_W, &cnt[3], 128, ((bx - 64) << 2) + wv, 1024, lane);

    } else {
        // ================= word layer 1 =================
        __shared__ float sX1[512];
        const int vw = ((bx - 192) << 2) + wv;       // hidden unit 0..511
        float4 wi0[4], wi1[4], wh0[4], wh1[4]; float bs[4];
        #pragma unroll
        for (int gq = 0; gq < 4; ++gq){
            const size_t rf = (size_t)(2048 + (gq << 9) + vw);
            const float4* pi = (const float4*)(wWih + rf*512) + lane*2;
            const float4* ph = (const float4*)(wWhh + rf*512) + lane*2;
            wi0[gq] = pi[0]; wi1[gq] = pi[1];
            wh0[gq] = ph[0]; wh1[gq] = ph[1];
            bs[gq] = wbih[rf] + wbhh[rf];
        }
        const float4* hv = (const float4*)(hwh + 512) + lane*2;
        const float4 hva = hv[0], hvb = hv[1];

        // prefetch this role's share of dec_W under char + w0 phases
        dec_prefetch(dec_W, &cnt[2], 128, 512 + ((bx - 192) << 2) + wv, 1024, lane);

        if (tid == 0) bar_wait(&cnt[2], 128);        // layer0 done
        __syncthreads();
        sX1[tid]       = gload(ws + 2048 + tid);
        sX1[256 + tid] = gload(ws + 2048 + 256 + tid);
        __syncthreads();
        {
            const float4 xa = ((const float4*)sX1)[lane*2];
            const float4 xb = ((const float4*)sX1)[lane*2 + 1];
            float ac[4];
            #pragma unroll
            for (int gq = 0; gq < 4; ++gq){
                float a = dot44(wi0[gq], xa) + dot44(wi1[gq], xb)
                        + dot44(wh0[gq], hva) + dot44(wh1[gq], hvb);
                #pragma unroll
                for (int m = 32; m >= 1; m >>= 1) a += __shfl_xor(a, m, 64);
                ac[gq] = a;
            }
            if (lane == 0){
                float gi = sigf(ac[0] + bs[0]);
                float gf = sigf(ac[1] + bs[1]);
                float gg = tanhf_(ac[2] + bs[2]);
                float go = sigf(ac[3] + bs[3]);
                float c = gf * hwc[512 + vw] + gi * gg;
                float h = go * tanhf_(c);
                gstore(ws + 2560 + vw, h);
                out[50000 + 512 + vw] = h;
                out[51024 + 512 + vw] = c;
            }
        }
        __syncthreads();
        if (tid == 0) bar_add(&cnt[3]);
    }

    // ================= decoder (all 320 blocks, 1280 waves, LLC-warm) =================
    __shared__ float sHW[512];
    if (tid == 0) bar_wait(&cnt[3], 128);
    __syncthreads();
    sHW[tid]       = gload(ws + 2560 + tid);
    sHW[256 + tid] = gload(ws + 2560 + 256 + tid);
    __syncthreads();
    {
        const float4 ha = ((const float4*)sHW)[lane*2];
        const float4 hb = ((const float4*)sHW)[lane*2 + 1];
        const int wid = (bx << 2) + wv;
        for (int r = wid; r < 50000; r += 1280){
            const float4* wp = (const float4*)(dec_W + (size_t)r*512) + lane*2;
            float acc = dot44(wp[0], ha) + dot44(wp[1], hb);
            #pragma unroll
            for (int m = 32; m >= 1; m >>= 1) acc += __shfl_xor(acc, m, 64);
            if (lane == 0) out[r] = acc + dec_b[r];
        }
    }
}

extern "C" void kernel_launch(void* const* d_in, const int* in_sizes, int n_in,
                              void* d_out, int out_size, void* d_ws, size_t ws_size,
                              hipStream_t stream)
{
    const int*   x_word   = (const int*)d_in[0];
    const int*   x_char   = (const int*)d_in[1];
    const float* hwh      = (const float*)d_in[2];
    const float* hwc      = (const float*)d_in[3];
    const float* hch      = (const float*)d_in[4];
    const float* hcc      = (const float*)d_in[5];
    const float* word_emb = (const float*)d_in[6];
    const float* wWih     = (const float*)d_in[7];
    const float* wWhh     = (const float*)d_in[8];
    const float* wbih     = (const float*)d_in[9];
    const float* wbhh     = (const float*)d_in[10];
    const float* dec_W    = (const float*)d_in[11];
    const float* dec_b    = (const float*)d_in[12];
    const float* char_emb = (const float*)d_in[13];
    const float* cWih     = (const float*)d_in[14];
    const float* cWhh     = (const float*)d_in[15];
    const float* cbih     = (const float*)d_in[16];
    const float* cbhh     = (const float*)d_in[17];
    const float* cte      = (const float*)d_in[18];
    const float* g_w      = (const float*)d_in[19];
    const float* g_b      = (const float*)d_in[20];

    float* ws  = (float*)d_ws;
    float* out = (float*)d_out;

    // zero the sync counters (ws byte offset 16384)
    hipMemsetAsync((void*)((char*)d_ws + 16384), 0, 64, stream);

    hipLaunchKernelGGL(k_fused, dim3(320), dim3(256), 0, stream,
        x_word, x_char, hwh, hwc, hch, hcc, word_emb,
        wWih, wWhh, wbih, wbhh, dec_W, dec_b,
        char_emb, cWih, cWhh, cbih, cbhh, cte, g_w, g_b,
        ws, out);
}

// Round 3
// 331.030 us; speedup vs baseline: 1.7972x; 1.0849x over previous
//
#include <hip/hip_runtime.h>
#include <stdint.h>

// GatedLSTM — single persistent-grid fused kernel, round 3.
// Round-2 structure + sync-traffic engineering:
//  * every atomic counter on its own 256B line (no shared-line LLC bank contention)
//  * dedicated one-shot char_done flag (char-step barrier line stays private to 64 blocks)
//  * long cross-phase waits poll with s_sleep(64) (~1.7us); only the char barrier polls fast
//  * dec_W prefetch runs flag-free to completion (self-terminating, ~7 iters/wave)
//  * decoder: 1-row lookahead to pipeline LLC latency
// All cross-block data/flags via RELAXED agent-scope atomics (sc1, LLC coherence point).
//
// ws float layout: 0 h1[2][256] | 512 h2[2][256] | 1280 c2[256] (published @t==12)
//                  1536 xcw[512] | 2048 hw1[512] | 2560 hw2[512] | 3072 g
//                  4096+ : int counters, 64-int (256B) spacing  (memset 2KB per launch)

#define SCOPE_AGT __HIP_MEMORY_SCOPE_AGENT

// counter indices (in ints, 64-int spacing = 256B lines)
#define CNT_CHAR   0      // char per-step barrier (64 adds/step)
#define CNT_CDONE  64     // char phase complete   (64 adds, once)
#define CNT_MIX    128    // mix barrier           (128 adds)
#define CNT_W0     192    // word layer0 done      (128 adds)
#define CNT_W1     256    // word layer1 done      (128 adds)

static __device__ __forceinline__ float dot4(float4 w, const float* p){
    return w.x*p[0] + w.y*p[1] + w.z*p[2] + w.w*p[3];
}
static __device__ __forceinline__ float dot44(float4 a, float4 b){
    return a.x*b.x + a.y*b.y + a.z*b.z + a.w*b.w;
}
static __device__ __forceinline__ float sigf(float x){ return 1.0f / (1.0f + __expf(-x)); }
static __device__ __forceinline__ float tanhf_(float x){
    x = fminf(fmaxf(x, -15.0f), 15.0f);
    float e = __expf(2.0f * x);
    return (e - 1.0f) / (e + 1.0f);
}

static __device__ __forceinline__ float gload(const float* p){
    return __hip_atomic_load(p, __ATOMIC_RELAXED, SCOPE_AGT);
}
static __device__ __forceinline__ void gstore(float* p, float v){
    __hip_atomic_store(p, v, __ATOMIC_RELAXED, SCOPE_AGT);
}
static __device__ __forceinline__ void bar_add(int* c){
    __hip_atomic_fetch_add(c, 1, __ATOMIC_RELAXED, SCOPE_AGT);
}
static __device__ __forceinline__ void bar_wait_fast(int* c, int tgt){
    while (__hip_atomic_load(c, __ATOMIC_RELAXED, SCOPE_AGT) < tgt)
        __builtin_amdgcn_s_sleep(2);      // ~128 cy between polls (64 pollers max)
}
static __device__ __forceinline__ void bar_wait_slow(int* c, int tgt){
    while (__hip_atomic_load(c, __ATOMIC_RELAXED, SCOPE_AGT) < tgt)
        __builtin_amdgcn_s_sleep(64);     // ~4096 cy (~1.7us) between polls
}

// Warm LLC with decoder rows; flag-free, self-terminating (~7 iterations).
static __device__ __forceinline__ void dec_prefetch(const float* __restrict__ dec_W,
        int start, int stride, int lane){
    float acc[8] = {0.f,0.f,0.f,0.f,0.f,0.f,0.f,0.f};
    for (int r = start; r < 50000; r += 8*stride){
        #pragma unroll
        for (int k = 0; k < 8; ++k){
            int rr = r + k * stride;
            if (rr < 50000) acc[k] += dec_W[(size_t)rr * 512 + lane * 8];
        }
    }
    float s = acc[0]+acc[1]+acc[2]+acc[3]+acc[4]+acc[5]+acc[6]+acc[7];
    asm volatile("" :: "v"(s));   // keep loads alive
}

__global__ __launch_bounds__(256, 2) void k_fused(
    const int* __restrict__ x_word, const int* __restrict__ x_char,
    const float* __restrict__ hwh, const float* __restrict__ hwc,
    const float* __restrict__ hch, const float* __restrict__ hcc,
    const float* __restrict__ word_emb,
    const float* __restrict__ wWih, const float* __restrict__ wWhh,
    const float* __restrict__ wbih, const float* __restrict__ wbhh,
    const float* __restrict__ dec_W, const float* __restrict__ dec_b,
    const float* __restrict__ char_emb,
    const float* __restrict__ cWih, const float* __restrict__ cWhh,
    const float* __restrict__ cbih, const float* __restrict__ cbhh,
    const float* __restrict__ cte,
    const float* __restrict__ g_w, const float* __restrict__ g_b,
    float* __restrict__ ws, float* __restrict__ out)
{
    const int tid  = threadIdx.x;
    const int bx   = blockIdx.x;
    const int lane = tid & 63;
    const int wv   = tid >> 6;
    int* cnt = (int*)(ws + 4096);

    if (bx < 64){
        // ================= char LSTM (13 steps, reg-resident weights & cells) =================
        __shared__ float sH1[256], sH2[256], sE[256], sg1[16], sg2[16];
        float* h1b = ws;
        float* h2b = ws + 512;

        const int rg = tid >> 4, lane16 = tid & 15;
        const int gate = rg & 3, uu = rg >> 2;
        const int u = (bx << 2) + uu;
        const int row = (gate << 8) + u, row2 = 1024 + row;

        float4 w1i[4], w1h[4], w2i[4], w2h[4];
        {
            const float4* p1i = (const float4*)(cWih + (size_t)row  * 256) + lane16 * 4;
            const float4* p1h = (const float4*)(cWhh + (size_t)row  * 256) + lane16 * 4;
            const float4* p2i = (const float4*)(cWih + (size_t)row2 * 256) + lane16 * 4;
            const float4* p2h = (const float4*)(cWhh + (size_t)row2 * 256) + lane16 * 4;
            #pragma unroll
            for (int j = 0; j < 4; ++j){ w1i[j]=p1i[j]; w1h[j]=p1h[j]; w2i[j]=p2i[j]; w2h[j]=p2h[j]; }
        }
        const float b1 = cbih[row]  + cbhh[row];
        const float b2 = cbih[row2] + cbhh[row2];

        // block-exclusive cell states in registers
        float c1r = 0.f, c2r = 0.f, h1fin = 0.f, h2fin = 0.f;
        if (tid < 4)      c1r = hcc[(bx<<2) + tid];
        else if (tid < 8) c2r = hcc[256 + (bx<<2) + (tid-4)];

        for (int t = 0; t <= 12; ++t){
            sH1[tid] = (t == 0) ? hch[tid] : gload(h1b + (t & 1)*256 + tid);
            if (t >= 1) sH2[tid] = (t == 1) ? hch[256 + tid]
                                            : gload(h2b + ((t-1) & 1)*256 + tid);
            if (t < 12) sE[tid] = char_emb[x_char[t]*256 + tid];
            __syncthreads();

            float a1 = 0.f, a2 = 0.f;
            if (t < 12){
                const float* xp = sE  + lane16*16;
                const float* hp = sH1 + lane16*16;
                #pragma unroll
                for (int j = 0; j < 4; ++j) a1 += dot4(w1i[j], xp + 4*j) + dot4(w1h[j], hp + 4*j);
            }
            if (t >= 1){
                const float* xp = sH1 + lane16*16;
                const float* hp = sH2 + lane16*16;
                #pragma unroll
                for (int j = 0; j < 4; ++j) a2 += dot4(w2i[j], xp + 4*j) + dot4(w2h[j], hp + 4*j);
            }
            #pragma unroll
            for (int m = 8; m >= 1; m >>= 1){
                a1 += __shfl_xor(a1, m, 64);
                a2 += __shfl_xor(a2, m, 64);
            }
            if (lane16 == 0){
                if (t < 12) sg1[rg] = a1 + b1;
                if (t >= 1) sg2[rg] = a2 + b2;
            }
            __syncthreads();

            if (tid < 4){
                if (t < 12){
                    int uh = (bx << 2) + tid;
                    float gi = sigf(sg1[tid*4+0]);
                    float gf = sigf(sg1[tid*4+1]);
                    float gg = tanhf_(sg1[tid*4+2]);
                    float go = sigf(sg1[tid*4+3]);
                    float c = gf * c1r + gi * gg;
                    c1r = c;
                    float h = go * tanhf_(c);
                    h1fin = h;
                    gstore(h1b + ((t+1) & 1)*256 + uh, h);
                }
            } else if (tid < 8){
                if (t >= 1){
                    int q = tid - 4;
                    int uh = (bx << 2) + q;
                    float gi = sigf(sg2[q*4+0]);
                    float gf = sigf(sg2[q*4+1]);
                    float gg = tanhf_(sg2[q*4+2]);
                    float go = sigf(sg2[q*4+3]);
                    float c = gf * c2r + gi * gg;
                    c2r = c;
                    float h = go * tanhf_(c);
                    h2fin = h;
                    if (t < 12) gstore(h2b + (t & 1)*256 + uh, h);
                    else        gstore(ws + 1280 + uh, c);   // publish final c2 for mix
                }
            }
            __syncthreads();   // drains storers' vmcnt before the arrive
            if (tid == 0){
                bar_add(&cnt[CNT_CHAR]);
                if (t < 12) bar_wait_fast(&cnt[CNT_CHAR], 64*(t+1));
            }
            __syncthreads();
        }
        // signal char completion on a dedicated line (c2 stores already drained)
        if (tid == 0) bar_add(&cnt[CNT_CDONE]);

        // final char states from registers (own-block data only)
        if (tid < 4){
            int uh = (bx << 2) + tid;
            out[52048 + uh] = h1fin;   // h_char_h layer0 (t==11)
            out[52560 + uh] = c1r;     // h_char_c layer0
        } else if (tid < 8){
            int uh = (bx << 2) + (tid - 4);
            out[52048 + 256 + uh] = h2fin;  // h_char_h layer1 (t==12)
            out[52560 + 256 + uh] = c2r;    // h_char_c layer1
        }

    } else if (bx < 192){
        // ================= gate + mix + word layer 0 =================
        __shared__ float sC2[256];
        __shared__ float sXCW[512];
        __shared__ float sMisc[8];
        const int vw = ((bx - 64) << 2) + wv;        // hidden unit 0..511
        float4 wi0[4], wi1[4], wh0[4], wh1[4]; float bs[4];
        #pragma unroll
        for (int gq = 0; gq < 4; ++gq){
            const size_t rf = (size_t)((gq << 9) + vw);
            const float4* pi = (const float4*)(wWih + rf*512) + lane*2;
            const float4* ph = (const float4*)(wWhh + rf*512) + lane*2;
            wi0[gq] = pi[0]; wi1[gq] = pi[1];
            wh0[gq] = ph[0]; wh1[gq] = ph[1];
            bs[gq] = wbih[rf] + wbhh[rf];
        }
        const float4* hv = (const float4*)(hwh) + lane*2;
        const float4 hva = hv[0], hvb = hv[1];
        const size_t wbase = (size_t)x_word[0] * 512;
        const float4* wep = (const float4*)(word_emb + wbase) + lane*2;
        const float4 wea = wep[0], web = wep[1];

        if (bx == 64){
            float p = g_w[2*tid]   * word_emb[wbase + 2*tid]
                    + g_w[2*tid+1] * word_emb[wbase + 2*tid+1];
            #pragma unroll
            for (int m = 32; m >= 1; m >>= 1) p += __shfl_xor(p, m, 64);
            if (lane == 0) sMisc[wv] = p;
            __syncthreads();
            if (tid == 0)
                gstore(ws + 3072, fmaxf(sMisc[0]+sMisc[1]+sMisc[2]+sMisc[3] + g_b[0], 0.0f));
        }

        // prefetch this role's share of dec_W under the char phase (flag-free)
        dec_prefetch(dec_W, ((bx - 64) << 2) + wv, 1024, lane);

        if (tid == 0) bar_wait_slow(&cnt[CNT_CDONE], 64);   // char done (c2 published)
        __syncthreads();
        sC2[tid] = gload(ws + 1280 + tid);
        __syncthreads();

        // mix: xcw[vw] = cte[vw,:] . c2
        {
            float4 cv  = ((const float4*)(cte + (size_t)vw*256))[lane];
            float4 c2v = ((const float4*)sC2)[lane];
            float acc = dot44(cv, c2v);
            #pragma unroll
            for (int m = 32; m >= 1; m >>= 1) acc += __shfl_xor(acc, m, 64);
            if (lane == 0) gstore(ws + 1536 + vw, acc);
        }
        __syncthreads();
        if (tid == 0){ bar_add(&cnt[CNT_MIX]); bar_wait_fast(&cnt[CNT_MIX], 128); }
        __syncthreads();
        sXCW[tid]       = gload(ws + 1536 + tid);
        sXCW[256 + tid] = gload(ws + 1536 + 256 + tid);
        if (tid == 0) sMisc[4] = gload(ws + 3072);
        __syncthreads();

        // word layer 0 (one unit per wave)
        {
            const float g  = sMisc[4];
            const float og = 1.0f - g;
            const float4 x0 = ((const float4*)sXCW)[lane*2];
            const float4 x1 = ((const float4*)sXCW)[lane*2 + 1];
            float4 xa, xb;
            xa.x = og*wea.x + g*x0.x; xa.y = og*wea.y + g*x0.y;
            xa.z = og*wea.z + g*x0.z; xa.w = og*wea.w + g*x0.w;
            xb.x = og*web.x + g*x1.x; xb.y = og*web.y + g*x1.y;
            xb.z = og*web.z + g*x1.z; xb.w = og*web.w + g*x1.w;
            float ac[4];
            #pragma unroll
            for (int gq = 0; gq < 4; ++gq){
                float a = dot44(wi0[gq], xa) + dot44(wi1[gq], xb)
                        + dot44(wh0[gq], hva) + dot44(wh1[gq], hvb);
                #pragma unroll
                for (int m = 32; m >= 1; m >>= 1) a += __shfl_xor(a, m, 64);
                ac[gq] = a;
            }
            if (lane == 0){
                float gi = sigf(ac[0] + bs[0]);
                float gf = sigf(ac[1] + bs[1]);
                float gg = tanhf_(ac[2] + bs[2]);
                float go = sigf(ac[3] + bs[3]);
                float c = gf * hwc[vw] + gi * gg;
                float h = go * tanhf_(c);
                gstore(ws + 2048 + vw, h);
                out[50000 + vw] = h;
                out[51024 + vw] = c;
            }
        }
        __syncthreads();
        if (tid == 0) bar_add(&cnt[CNT_W0]);

    } else {
        // ================= word layer 1 =================
        __shared__ float sX1[512];
        const int vw = ((bx - 192) << 2) + wv;       // hidden unit 0..511
        float4 wi0[4], wi1[4], wh0[4], wh1[4]; float bs[4];
        #pragma unroll
        for (int gq = 0; gq < 4; ++gq){
            const size_t rf = (size_t)(2048 + (gq << 9) + vw);
            const float4* pi = (const float4*)(wWih + rf*512) + lane*2;
            const float4* ph = (const float4*)(wWhh + rf*512) + lane*2;
            wi0[gq] = pi[0]; wi1[gq] = pi[1];
            wh0[gq] = ph[0]; wh1[gq] = ph[1];
            bs[gq] = wbih[rf] + wbhh[rf];
        }
        const float4* hv = (const float4*)(hwh + 512) + lane*2;
        const float4 hva = hv[0], hvb = hv[1];

        // prefetch this role's share of dec_W under the char + w0 phases (flag-free)
        dec_prefetch(dec_W, 512 + ((bx - 192) << 2) + wv, 1024, lane);

        if (tid == 0) bar_wait_slow(&cnt[CNT_W0], 128);     // layer0 done
        __syncthreads();
        sX1[tid]       = gload(ws + 2048 + tid);
        sX1[256 + tid] = gload(ws + 2048 + 256 + tid);
        __syncthreads();
        {
            const float4 xa = ((const float4*)sX1)[lane*2];
            const float4 xb = ((const float4*)sX1)[lane*2 + 1];
            float ac[4];
            #pragma unroll
            for (int gq = 0; gq < 4; ++gq){
                float a = dot44(wi0[gq], xa) + dot44(wi1[gq], xb)
                        + dot44(wh0[gq], hva) + dot44(wh1[gq], hvb);
                #pragma unroll
                for (int m = 32; m >= 1; m >>= 1) a += __shfl_xor(a, m, 64);
                ac[gq] = a;
            }
            if (lane == 0){
                float gi = sigf(ac[0] + bs[0]);
                float gf = sigf(ac[1] + bs[1]);
                float gg = tanhf_(ac[2] + bs[2]);
                float go = sigf(ac[3] + bs[3]);
                float c = gf * hwc[512 + vw] + gi * gg;
                float h = go * tanhf_(c);
                gstore(ws + 2560 + vw, h);
                out[50000 + 512 + vw] = h;
                out[51024 + 512 + vw] = c;
            }
        }
        __syncthreads();
        if (tid == 0) bar_add(&cnt[CNT_W1]);
    }

    // ================= decoder (all 320 blocks, 1280 waves, LLC-warm) =================
    __shared__ float sHW[512];
    if (tid == 0) bar_wait_slow(&cnt[CNT_W1], 128);
    __syncthreads();
    sHW[tid]       = gload(ws + 2560 + tid);
    sHW[256 + tid] = gload(ws + 2560 + 256 + tid);
    __syncthreads();
    {
        const float4 ha = ((const float4*)sHW)[lane*2];
        const float4 hb = ((const float4*)sHW)[lane*2 + 1];
        const int wid = (bx << 2) + wv;
        // 1-row lookahead to pipeline LLC latency
        int r = wid;
        float4 a0 = make_float4(0,0,0,0), b0 = a0;
        if (r < 50000){
            const float4* wp = (const float4*)(dec_W + (size_t)r*512) + lane*2;
            a0 = wp[0]; b0 = wp[1];
        }
        while (r < 50000){
            const int rn = r + 1280;
            float4 a1 = make_float4(0,0,0,0), b1 = a1;
            if (rn < 50000){
                const float4* wp = (const float4*)(dec_W + (size_t)rn*512) + lane*2;
                a1 = wp[0]; b1 = wp[1];
            }
            float acc = dot44(a0, ha) + dot44(b0, hb);
            #pragma unroll
            for (int m = 32; m >= 1; m >>= 1) acc += __shfl_xor(acc, m, 64);
            if (lane == 0) out[r] = acc + dec_b[r];
            r = rn; a0 = a1; b0 = b1;
        }
    }
}

extern "C" void kernel_launch(void* const* d_in, const int* in_sizes, int n_in,
                              void* d_out, int out_size, void* d_ws, size_t ws_size,
                              hipStream_t stream)
{
    const int*   x_word   = (const int*)d_in[0];
    const int*   x_char   = (const int*)d_in[1];
    const float* hwh      = (const float*)d_in[2];
    const float* hwc      = (const float*)d_in[3];
    const float* hch      = (const float*)d_in[4];
    const float* hcc      = (const float*)d_in[5];
    const float* word_emb = (const float*)d_in[6];
    const float* wWih     = (const float*)d_in[7];
    const float* wWhh     = (const float*)d_in[8];
    const float* wbih     = (const float*)d_in[9];
    const float* wbhh     = (const float*)d_in[10];
    const float* dec_W    = (const float*)d_in[11];
    const float* dec_b    = (const float*)d_in[12];
    const float* char_emb = (const float*)d_in[13];
    const float* cWih     = (const float*)d_in[14];
    const float* cWhh     = (const float*)d_in[15];
    const float* cbih     = (const float*)d_in[16];
    const float* cbhh     = (const float*)d_in[17];
    const float* cte      = (const float*)d_in[18];
    const float* g_w      = (const float*)d_in[19];
    const float* g_b      = (const float*)d_in[20];

    float* ws  = (float*)d_ws;
    float* out = (float*)d_out;

    // zero the sync counters (ws byte offset 16384, five 256B lines -> 2KB)
    hipMemsetAsync((void*)((char*)d_ws + 16384), 0, 2048, stream);

    hipLaunchKernelGGL(k_fused, dim3(320), dim3(256), 0, stream,
        x_word, x_char, hwh, hwc, hch, hcc, word_emb,
        wWih, wWhh, wbih, wbhh, dec_W, dec_b,
        char_emb, cWih, cWhh, cbih, cbhh, cte, g_w, g_b,
        ws, out);
}

// Round 4
// 306.242 us; speedup vs baseline: 1.9427x; 1.0809x over previous
//
#include <hip/hip_runtime.h>
#include <stdint.h>

// GatedLSTM — single persistent-grid fused kernel, round 4.
// Sync rebuilt: NO central atomic counters (round-3 evidence: 64 same-line RMWs
// per char step serialize at LLC ≈ 8.5us/step). Instead:
//  * char step barrier: per-block {h-values, seq} lines (64B each, double-buffered
//    by step parity); publisher = plain agent stores + own seq word; consumer =
//    wave0, lane i polls seq[i] (ballot), then loads block i's h (ordered after seq).
//  * phase flags: per-block stores, ballot-polled; cdone condensed by block 0.
//  * decoder: 8 rows/batch/wave, 8 lanes/row, 16 float4 in flight (5 latency stalls
//    instead of 40).
// All cross-block traffic via RELAXED agent-scope atomics (LLC coherence point).
//
// ws float layout: 1280 c2[256] | 1536 xcw[512] | 2048 hw1[512] | 2560 hw2[512] | 3072 g
// int flag region at ws+4096 floats (byte 16384), memset 16KB per launch:
//   seq[2][64] ints 0..127 | w0f[128] ints 128..255 | w1f[128] ints 256..383
//   cdone int 512 | fdata floats ws+4864 (2x64 blocks x 16 floats, 64B lines)

#define SCOPE_AGT __HIP_MEMORY_SCOPE_AGENT
#define ALL64 0xFFFFFFFFFFFFFFFFull

static __device__ __forceinline__ float dot4(float4 w, const float* p){
    return w.x*p[0] + w.y*p[1] + w.z*p[2] + w.w*p[3];
}
static __device__ __forceinline__ float dot44(float4 a, float4 b){
    return a.x*b.x + a.y*b.y + a.z*b.z + a.w*b.w;
}
static __device__ __forceinline__ float sigf(float x){ return 1.0f / (1.0f + __expf(-x)); }
static __device__ __forceinline__ float tanhf_(float x){
    x = fminf(fmaxf(x, -15.0f), 15.0f);
    float e = __expf(2.0f * x);
    return (e - 1.0f) / (e + 1.0f);
}

static __device__ __forceinline__ float gload(const float* p){
    return __hip_atomic_load(p, __ATOMIC_RELAXED, SCOPE_AGT);
}
static __device__ __forceinline__ void gstore(float* p, float v){
    __hip_atomic_store(p, v, __ATOMIC_RELAXED, SCOPE_AGT);
}
static __device__ __forceinline__ int gload_i(const int* p){
    return __hip_atomic_load(p, __ATOMIC_RELAXED, SCOPE_AGT);
}
static __device__ __forceinline__ void gstore_i(int* p, int v){
    __hip_atomic_store(p, v, __ATOMIC_RELAXED, SCOPE_AGT);
}
static __device__ __forceinline__ unsigned long long gload_ll(const float* p){
    return __hip_atomic_load((const unsigned long long*)p, __ATOMIC_RELAXED, SCOPE_AGT);
}
static __device__ __forceinline__ unsigned long long gload_ll_i(const int* p){
    return __hip_atomic_load((const unsigned long long*)p, __ATOMIC_RELAXED, SCOPE_AGT);
}

// Warm LLC with decoder rows; flag-free, self-terminating (~7 iterations).
static __device__ __forceinline__ void dec_prefetch(const float* __restrict__ dec_W,
        int start, int stride, int lane){
    float acc[8] = {0.f,0.f,0.f,0.f,0.f,0.f,0.f,0.f};
    for (int r = start; r < 50000; r += 8*stride){
        #pragma unroll
        for (int k = 0; k < 8; ++k){
            int rr = r + k * stride;
            if (rr < 50000) acc[k] += dec_W[(size_t)rr * 512 + lane * 8];
        }
    }
    float s = acc[0]+acc[1]+acc[2]+acc[3]+acc[4]+acc[5]+acc[6]+acc[7];
    asm volatile("" :: "v"(s));   // keep loads alive
}

__global__ __launch_bounds__(256, 2) void k_fused(
    const int* __restrict__ x_word, const int* __restrict__ x_char,
    const float* __restrict__ hwh, const float* __restrict__ hwc,
    const float* __restrict__ hch, const float* __restrict__ hcc,
    const float* __restrict__ word_emb,
    const float* __restrict__ wWih, const float* __restrict__ wWhh,
    const float* __restrict__ wbih, const float* __restrict__ wbhh,
    const float* __restrict__ dec_W, const float* __restrict__ dec_b,
    const float* __restrict__ char_emb,
    const float* __restrict__ cWih, const float* __restrict__ cWhh,
    const float* __restrict__ cbih, const float* __restrict__ cbhh,
    const float* __restrict__ cte,
    const float* __restrict__ g_w, const float* __restrict__ g_b,
    float* __restrict__ ws, float* __restrict__ out)
{
    const int tid  = threadIdx.x;
    const int bx   = blockIdx.x;
    const int lane = tid & 63;
    const int wv   = tid >> 6;
    int*   ws_i  = (int*)(ws + 4096);
    int*   seqf  = ws_i;            // [2][64]
    int*   w0f   = ws_i + 128;      // [128]
    int*   w1f   = ws_i + 256;      // [128]
    int*   cdone = ws_i + 512;
    float* fdata = ws + 4864;       // [2][64][16]

    __shared__ float sHW[512];      // decoder h (all roles)

    if (bx < 64){
        // ================= char LSTM (13 steps, reg weights, flag-line exchange) =================
        __shared__ float sH1[256], sH2[256], sE[256], sg1[16], sg2[16];

        const int rg = tid >> 4, lane16 = tid & 15;
        const int gate = rg & 3, uu = rg >> 2;
        const int u = (bx << 2) + uu;
        const int row = (gate << 8) + u, row2 = 1024 + row;

        float4 w1i[4], w1h[4], w2i[4], w2h[4];
        {
            const float4* p1i = (const float4*)(cWih + (size_t)row  * 256) + lane16 * 4;
            const float4* p1h = (const float4*)(cWhh + (size_t)row  * 256) + lane16 * 4;
            const float4* p2i = (const float4*)(cWih + (size_t)row2 * 256) + lane16 * 4;
            const float4* p2h = (const float4*)(cWhh + (size_t)row2 * 256) + lane16 * 4;
            #pragma unroll
            for (int j = 0; j < 4; ++j){ w1i[j]=p1i[j]; w1h[j]=p1h[j]; w2i[j]=p2i[j]; w2h[j]=p2h[j]; }
        }
        const float b1 = cbih[row]  + cbhh[row];
        const float b2 = cbih[row2] + cbhh[row2];

        float c1r = 0.f, c2r = 0.f, h1fin = 0.f, h2fin = 0.f;
        if (tid < 4)      c1r = hcc[(bx<<2) + tid];
        else if (tid < 8) c2r = hcc[256 + (bx<<2) + (tid-4)];

        for (int t = 0; t <= 12; ++t){
            // -------- acquire step inputs --------
            if (t == 0){
                sH1[tid] = hch[tid];
            } else {
                if (t == 1) sH2[tid] = hch[256 + tid];
                if (tid < 64){
                    const int p = (t - 1) & 1;
                    const int* sq = seqf + p*64;
                    // poll seq (per-block lines, no RMW anywhere)
                    while (true){
                        int v = gload_i(sq + tid);
                        if (__ballot(v >= t) == ALL64) break;
                    }
                    // data load strictly AFTER seq observed (LLC-ordered)
                    const float* dl = fdata + (size_t)(p*64 + tid)*16;
                    union { unsigned long long u; float f[2]; } q0,q1,q2,q3;
                    q0.u = gload_ll(dl + 0);
                    q1.u = gload_ll(dl + 2);
                    q2.u = gload_ll(dl + 4);
                    q3.u = gload_ll(dl + 6);
                    sH1[4*tid+0] = q0.f[0]; sH1[4*tid+1] = q0.f[1];
                    sH1[4*tid+2] = q1.f[0]; sH1[4*tid+3] = q1.f[1];
                    if (t >= 2){
                        sH2[4*tid+0] = q2.f[0]; sH2[4*tid+1] = q2.f[1];
                        sH2[4*tid+2] = q3.f[0]; sH2[4*tid+3] = q3.f[1];
                    }
                }
            }
            if (t < 12) sE[tid] = char_emb[x_char[t]*256 + tid];
            __syncthreads();

            // -------- gate dots --------
            float a1 = 0.f, a2 = 0.f;
            if (t < 12){
                const float* xp = sE  + lane16*16;
                const float* hp = sH1 + lane16*16;
                #pragma unroll
                for (int j = 0; j < 4; ++j) a1 += dot4(w1i[j], xp + 4*j) + dot4(w1h[j], hp + 4*j);
            }
            if (t >= 1){
                const float* xp = sH1 + lane16*16;
                const float* hp = sH2 + lane16*16;
                #pragma unroll
                for (int j = 0; j < 4; ++j) a2 += dot4(w2i[j], xp + 4*j) + dot4(w2h[j], hp + 4*j);
            }
            #pragma unroll
            for (int m = 8; m >= 1; m >>= 1){
                a1 += __shfl_xor(a1, m, 64);
                a2 += __shfl_xor(a2, m, 64);
            }
            if (lane16 == 0){
                if (t < 12) sg1[rg] = a1 + b1;
                if (t >= 1) sg2[rg] = a2 + b2;
            }
            __syncthreads();

            // -------- cell update + publish --------
            const int p2 = t & 1;
            float* dst = fdata + (size_t)(p2*64 + bx)*16;
            if (tid < 4){
                if (t < 12){
                    float gi = sigf(sg1[tid*4+0]);
                    float gf = sigf(sg1[tid*4+1]);
                    float gg = tanhf_(sg1[tid*4+2]);
                    float go = sigf(sg1[tid*4+3]);
                    float c = gf * c1r + gi * gg;
                    c1r = c;
                    float h = go * tanhf_(c);
                    h1fin = h;
                    gstore(dst + tid, h);
                }
            } else if (tid < 8){
                if (t >= 1){
                    int q = tid - 4;
                    float gi = sigf(sg2[q*4+0]);
                    float gf = sigf(sg2[q*4+1]);
                    float gg = tanhf_(sg2[q*4+2]);
                    float go = sigf(sg2[q*4+3]);
                    float c = gf * c2r + gi * gg;
                    c2r = c;
                    float h = go * tanhf_(c);
                    h2fin = h;
                    if (t < 12) gstore(dst + 4 + q, h);
                    else        gstore(ws + 1280 + (bx<<2) + q, c);  // final c2 for mix
                }
            }
            __syncthreads();   // drains publish stores (vmcnt=0 before barrier)
            if (tid == 0) gstore_i(seqf + p2*64 + bx, t + 1);
        }

        // final char states from registers
        if (tid < 4){
            int uh = (bx << 2) + tid;
            out[52048 + uh] = h1fin;   // h_char_h layer0 (t==11)
            out[52560 + uh] = c1r;     // h_char_c layer0
        } else if (tid < 8){
            int uh = (bx << 2) + (tid - 4);
            out[52048 + 256 + uh] = h2fin;  // h_char_h layer1 (t==12)
            out[52560 + 256 + uh] = c2r;    // h_char_c layer1
        }

        // block 0 condenses "all char blocks done" into one word
        if (bx == 0 && tid < 64){
            while (true){
                int v = gload_i(seqf + tid);      // parity 0, step 12 -> seq 13
                if (__ballot(v >= 13) == ALL64) break;
            }
            if (tid == 0) gstore_i(cdone, 1);
        }

    } else if (bx < 192){
        // ================= gate + mix + word layer 0 =================
        __shared__ float sC2[256];
        __shared__ float sXCW[512];
        __shared__ float sMisc[8];
        const int vw = ((bx - 64) << 2) + wv;        // hidden unit 0..511
        float4 wi0[4], wi1[4], wh0[4], wh1[4]; float bs[4];
        #pragma unroll
        for (int gq = 0; gq < 4; ++gq){
            const size_t rf = (size_t)((gq << 9) + vw);
            const float4* pi = (const float4*)(wWih + rf*512) + lane*2;
            const float4* ph = (const float4*)(wWhh + rf*512) + lane*2;
            wi0[gq] = pi[0]; wi1[gq] = pi[1];
            wh0[gq] = ph[0]; wh1[gq] = ph[1];
            bs[gq] = wbih[rf] + wbhh[rf];
        }
        const float4* hv = (const float4*)(hwh) + lane*2;
        const float4 hva = hv[0], hvb = hv[1];
        const size_t wbase = (size_t)x_word[0] * 512;
        const float4* wep = (const float4*)(word_emb + wbase) + lane*2;
        const float4 wea = wep[0], web = wep[1];

        if (bx == 64){
            float p = g_w[2*tid]   * word_emb[wbase + 2*tid]
                    + g_w[2*tid+1] * word_emb[wbase + 2*tid+1];
            #pragma unroll
            for (int m = 32; m >= 1; m >>= 1) p += __shfl_xor(p, m, 64);
            if (lane == 0) sMisc[wv] = p;
            __syncthreads();
            if (tid == 0)
                gstore(ws + 3072, fmaxf(sMisc[0]+sMisc[1]+sMisc[2]+sMisc[3] + g_b[0], 0.0f));
        }

        // prefetch this role's share of dec_W under the char phase (flag-free)
        dec_prefetch(dec_W, ((bx - 64) << 2) + wv, 1024, lane);

        if (tid == 0){ while (gload_i(cdone) < 1) __builtin_amdgcn_s_sleep(8); }
        __syncthreads();
        sC2[tid] = gload(ws + 1280 + tid);
        __syncthreads();

        // mix: xcw[vw] = cte[vw,:] . c2
        {
            float4 cv  = ((const float4*)(cte + (size_t)vw*256))[lane];
            float4 c2v = ((const float4*)sC2)[lane];
            float acc = dot44(cv, c2v);
            #pragma unroll
            for (int m = 32; m >= 1; m >>= 1) acc += __shfl_xor(acc, m, 64);
            if (lane == 0) gstore(ws + 1536 + vw, acc);
        }
        __syncthreads();                       // drain xcw stores
        if (tid == 0) gstore_i(w0f + (bx - 64), 1);
        if (tid < 64){
            while (true){
                unsigned long long v = gload_ll_i(w0f + 2*tid);
                int lo = (int)(v & 0xffffffffu), hi = (int)(v >> 32);
                if (__ballot(lo >= 1 && hi >= 1) == ALL64) break;
            }
        }
        __syncthreads();
        sXCW[tid]       = gload(ws + 1536 + tid);
        sXCW[256 + tid] = gload(ws + 1536 + 256 + tid);
        if (tid == 0) sMisc[4] = gload(ws + 3072);
        __syncthreads();

        // word layer 0 (one unit per wave)
        {
            const float g  = sMisc[4];
            const float og = 1.0f - g;
            const float4 x0 = ((const float4*)sXCW)[lane*2];
            const float4 x1 = ((const float4*)sXCW)[lane*2 + 1];
            float4 xa, xb;
            xa.x = og*wea.x + g*x0.x; xa.y = og*wea.y + g*x0.y;
            xa.z = og*wea.z + g*x0.z; xa.w = og*wea.w + g*x0.w;
            xb.x = og*web.x + g*x1.x; xb.y = og*web.y + g*x1.y;
            xb.z = og*web.z + g*x1.z; xb.w = og*web.w + g*x1.w;
            float ac[4];
            #pragma unroll
            for (int gq = 0; gq < 4; ++gq){
                float a = dot44(wi0[gq], xa) + dot44(wi1[gq], xb)
                        + dot44(wh0[gq], hva) + dot44(wh1[gq], hvb);
                #pragma unroll
                for (int m = 32; m >= 1; m >>= 1) a += __shfl_xor(a, m, 64);
                ac[gq] = a;
            }
            if (lane == 0){
                float gi = sigf(ac[0] + bs[0]);
                float gf = sigf(ac[1] + bs[1]);
                float gg = tanhf_(ac[2] + bs[2]);
                float go = sigf(ac[3] + bs[3]);
                float c = gf * hwc[vw] + gi * gg;
                float h = go * tanhf_(c);
                gstore(ws + 2048 + vw, h);
                out[50000 + vw] = h;
                out[51024 + vw] = c;
            }
        }
        __syncthreads();                       // drain hw1 stores
        if (tid == 0) gstore_i(w0f + (bx - 64), 2);

    } else {
        // ================= word layer 1 =================
        __shared__ float sX1[512];
        const int vw = ((bx - 192) << 2) + wv;       // hidden unit 0..511
        float4 wi0[4], wi1[4], wh0[4], wh1[4]; float bs[4];
        #pragma unroll
        for (int gq = 0; gq < 4; ++gq){
            const size_t rf = (size_t)(2048 + (gq << 9) + vw);
            const float4* pi = (const float4*)(wWih + rf*512) + lane*2;
            const float4* ph = (const float4*)(wWhh + rf*512) + lane*2;
            wi0[gq] = pi[0]; wi1[gq] = pi[1];
            wh0[gq] = ph[0]; wh1[gq] = ph[1];
            bs[gq] = wbih[rf] + wbhh[rf];
        }
        const float4* hv = (const float4*)(hwh + 512) + lane*2;
        const float4 hva = hv[0], hvb = hv[1];

        // prefetch this role's share of dec_W under the char + w0 phases (flag-free)
        dec_prefetch(dec_W, 512 + ((bx - 192) << 2) + wv, 1024, lane);

        if (tid < 64){
            while (true){
                unsigned long long v = gload_ll_i(w0f + 2*tid);
                int lo = (int)(v & 0xffffffffu), hi = (int)(v >> 32);
                if (__ballot(lo >= 2 && hi >= 2) == ALL64) break;
                __builtin_amdgcn_s_sleep(2);
            }
        }
        __syncthreads();
        sX1[tid]       = gload(ws + 2048 + tid);
        sX1[256 + tid] = gload(ws + 2048 + 256 + tid);
        __syncthreads();
        {
            const float4 xa = ((const float4*)sX1)[lane*2];
            const float4 xb = ((const float4*)sX1)[lane*2 + 1];
            float ac[4];
            #pragma unroll
            for (int gq = 0; gq < 4; ++gq){
                float a = dot44(wi0[gq], xa) + dot44(wi1[gq], xb)
                        + dot44(wh0[gq], hva) + dot44(wh1[gq], hvb);
                #pragma unroll
                for (int m = 32; m >= 1; m >>= 1) a += __shfl_xor(a, m, 64);
                ac[gq] = a;
            }
            if (lane == 0){
                float gi = sigf(ac[0] + bs[0]);
                float gf = sigf(ac[1] + bs[1]);
                float gg = tanhf_(ac[2] + bs[2]);
                float go = sigf(ac[3] + bs[3]);
                float c = gf * hwc[512 + vw] + gi * gg;
                float h = go * tanhf_(c);
                gstore(ws + 2560 + vw, h);
                out[50000 + 512 + vw] = h;
                out[51024 + 512 + vw] = c;
            }
        }
        __syncthreads();                       // drain hw2 stores
        if (tid == 0) gstore_i(w1f + (bx - 192), 1);
    }

    // ================= decoder (all 320 blocks, 1280 waves, LLC-warm) =================
    if (tid < 64){
        while (true){
            unsigned long long v = gload_ll_i(w1f + 2*tid);
            int lo = (int)(v & 0xffffffffu), hi = (int)(v >> 32);
            if (__ballot(lo >= 1 && hi >= 1) == ALL64) break;
            __builtin_amdgcn_s_sleep(4);
        }
    }
    __syncthreads();
    sHW[tid]       = gload(ws + 2560 + tid);
    sHW[256 + tid] = gload(ws + 2560 + 256 + tid);
    __syncthreads();
    {
        // 8 rows per batch per wave; 8 lanes per row (64 floats/lane);
        // 16 float4 loads in flight, h from LDS (same-address broadcast).
        const int wid = (bx << 2) + wv;
        const int rr = lane >> 3, cc = lane & 7;
        const float4* hq = (const float4*)sHW + cc*16;
        for (int gb = wid; gb < 6250; gb += 1280){
            const int r = gb*8 + rr;
            const float4* wp = (const float4*)(dec_W + (size_t)r*512 + cc*64);
            float4 wbuf[8];
            float acc = 0.f;
            #pragma unroll
            for (int j = 0; j < 8; ++j) wbuf[j] = wp[j];
            #pragma unroll
            for (int j = 0; j < 8; ++j) acc += dot44(wbuf[j], hq[j]);
            #pragma unroll
            for (int j = 0; j < 8; ++j) wbuf[j] = wp[8 + j];
            #pragma unroll
            for (int j = 0; j < 8; ++j) acc += dot44(wbuf[j], hq[8 + j]);
            acc += __shfl_xor(acc, 1, 64);
            acc += __shfl_xor(acc, 2, 64);
            acc += __shfl_xor(acc, 4, 64);
            if (cc == 0) out[r] = acc + dec_b[r];
        }
    }
}

extern "C" void kernel_launch(void* const* d_in, const int* in_sizes, int n_in,
                              void* d_out, int out_size, void* d_ws, size_t ws_size,
                              hipStream_t stream)
{
    const int*   x_word   = (const int*)d_in[0];
    const int*   x_char   = (const int*)d_in[1];
    const float* hwh      = (const float*)d_in[2];
    const float* hwc      = (const float*)d_in[3];
    const float* hch      = (const float*)d_in[4];
    const float* hcc      = (const float*)d_in[5];
    const float* word_emb = (const float*)d_in[6];
    const float* wWih     = (const float*)d_in[7];
    const float* wWhh     = (const float*)d_in[8];
    const float* wbih     = (const float*)d_in[9];
    const float* wbhh     = (const float*)d_in[10];
    const float* dec_W    = (const float*)d_in[11];
    const float* dec_b    = (const float*)d_in[12];
    const float* char_emb = (const float*)d_in[13];
    const float* cWih     = (const float*)d_in[14];
    const float* cWhh     = (const float*)d_in[15];
    const float* cbih     = (const float*)d_in[16];
    const float* cbhh     = (const float*)d_in[17];
    const float* cte      = (const float*)d_in[18];
    const float* g_w      = (const float*)d_in[19];
    const float* g_b      = (const float*)d_in[20];

    float* ws  = (float*)d_ws;
    float* out = (float*)d_out;

    // zero the flag/exchange region (ws bytes 16384..32767)
    hipMemsetAsync((void*)((char*)d_ws + 16384), 0, 16384, stream);

    hipLaunchKernelGGL(k_fused, dim3(320), dim3(256), 0, stream,
        x_word, x_char, hwh, hwc, hch, hcc, word_emb,
        wWih, wWhh, wbih, wbhh, dec_W, dec_b,
        char_emb, cWih, cWhh, cbih, cbhh, cte, g_w, g_b,
        ws, out);
}

// Round 5
// 299.427 us; speedup vs baseline: 1.9869x; 1.0228x over previous
//
#include <hip/hip_runtime.h>
#include <stdint.h>

// GatedLSTM — single persistent-grid fused kernel, round 5.
// Round-4 evidence: dec_W prefetch (102MB) congests fabric/HBM concurrently with the
// latency-critical char phase -> LLC round-trips inflate 3-5x. Round 5:
//  * NO prefetch. Decoder streams dec_W from HBM with 1280 coalesced waves (~18us).
//  * char step exchange: tag-in-data {h, float(t+1)} 8B atomic pairs; consumers poll
//    the data words directly (tag equality) -> 1 LLC round trip per step, not 2.
//  * char-done condensed by block 0 into 64 spread cdone lines (<=2 pollers/line);
//    mix blocks read the c2 pairs directly.
//  * decoder: 2 rows/wave, 32 lanes/row, fully coalesced 512B segments, h in regs.
// All cross-block traffic via RELAXED agent-scope atomics (LLC coherence point).
//
// ws float layout: 1536 xcw[512] | 2048 hw1[512] | 2560 hw2[512] | 3072 g
// int region at ws_i = (int*)(ws+4096)  [memset 32KB from byte 16384 per launch]:
//   w0f ints [0..127] | w1f ints [128..255] | cdone lines [256 + j*32], j<64
// fdata pairs at ws+6400 floats: [parity 2][block 64][32 floats], pair k at +2k

#define SCOPE_AGT __HIP_MEMORY_SCOPE_AGENT
#define ALL64 0xFFFFFFFFFFFFFFFFull

static __device__ __forceinline__ float dot4(float4 w, const float* p){
    return w.x*p[0] + w.y*p[1] + w.z*p[2] + w.w*p[3];
}
static __device__ __forceinline__ float dot44(float4 a, float4 b){
    return a.x*b.x + a.y*b.y + a.z*b.z + a.w*b.w;
}
static __device__ __forceinline__ float sigf(float x){ return 1.0f / (1.0f + __expf(-x)); }
static __device__ __forceinline__ float tanhf_(float x){
    x = fminf(fmaxf(x, -15.0f), 15.0f);
    float e = __expf(2.0f * x);
    return (e - 1.0f) / (e + 1.0f);
}

static __device__ __forceinline__ float gload(const float* p){
    return __hip_atomic_load(p, __ATOMIC_RELAXED, SCOPE_AGT);
}
static __device__ __forceinline__ void gstore(float* p, float v){
    __hip_atomic_store(p, v, __ATOMIC_RELAXED, SCOPE_AGT);
}
static __device__ __forceinline__ int gload_i(const int* p){
    return __hip_atomic_load(p, __ATOMIC_RELAXED, SCOPE_AGT);
}
static __device__ __forceinline__ void gstore_i(int* p, int v){
    __hip_atomic_store(p, v, __ATOMIC_RELAXED, SCOPE_AGT);
}
static __device__ __forceinline__ unsigned long long gload_ll(const float* p){
    return __hip_atomic_load((const unsigned long long*)p, __ATOMIC_RELAXED, SCOPE_AGT);
}
static __device__ __forceinline__ void gstore_ll(float* p, unsigned long long v){
    __hip_atomic_store((unsigned long long*)p, v, __ATOMIC_RELAXED, SCOPE_AGT);
}

union PairU { unsigned long long u; float f[2]; };

__global__ __launch_bounds__(256, 2) void k_fused(
    const int* __restrict__ x_word, const int* __restrict__ x_char,
    const float* __restrict__ hwh, const float* __restrict__ hwc,
    const float* __restrict__ hch, const float* __restrict__ hcc,
    const float* __restrict__ word_emb,
    const float* __restrict__ wWih, const float* __restrict__ wWhh,
    const float* __restrict__ wbih, const float* __restrict__ wbhh,
    const float* __restrict__ dec_W, const float* __restrict__ dec_b,
    const float* __restrict__ char_emb,
    const float* __restrict__ cWih, const float* __restrict__ cWhh,
    const float* __restrict__ cbih, const float* __restrict__ cbhh,
    const float* __restrict__ cte,
    const float* __restrict__ g_w, const float* __restrict__ g_b,
    float* __restrict__ ws, float* __restrict__ out)
{
    const int tid  = threadIdx.x;
    const int bx   = blockIdx.x;
    const int lane = tid & 63;
    const int wv   = tid >> 6;
    int*   ws_i  = (int*)(ws + 4096);
    int*   w0f   = ws_i;            // [128]
    int*   w1f   = ws_i + 128;      // [128]
    int*   cdone = ws_i + 256;      // 64 lines at stride 32 ints
    float* fdata = ws + 6400;       // [2][64][32] floats; pair k at +2k

    __shared__ float sHW[512];      // decoder h (all roles)

    if (bx < 64){
        // ================= char LSTM (13 steps, reg weights, pair exchange) =================
        __shared__ float sH1[256], sH2[256], sE[256], sg1[16], sg2[16];

        const int rg = tid >> 4, lane16 = tid & 15;
        const int gate = rg & 3, uu = rg >> 2;
        const int u = (bx << 2) + uu;
        const int row = (gate << 8) + u, row2 = 1024 + row;

        float4 w1i[4], w1h[4], w2i[4], w2h[4];
        {
            const float4* p1i = (const float4*)(cWih + (size_t)row  * 256) + lane16 * 4;
            const float4* p1h = (const float4*)(cWhh + (size_t)row  * 256) + lane16 * 4;
            const float4* p2i = (const float4*)(cWih + (size_t)row2 * 256) + lane16 * 4;
            const float4* p2h = (const float4*)(cWhh + (size_t)row2 * 256) + lane16 * 4;
            #pragma unroll
            for (int j = 0; j < 4; ++j){ w1i[j]=p1i[j]; w1h[j]=p1h[j]; w2i[j]=p2i[j]; w2h[j]=p2h[j]; }
        }
        const float b1 = cbih[row]  + cbhh[row];
        const float b2 = cbih[row2] + cbhh[row2];

        float c1r = 0.f, c2r = 0.f, h1fin = 0.f, h2fin = 0.f;
        if (tid < 4)      c1r = hcc[(bx<<2) + tid];
        else if (tid < 8) c2r = hcc[256 + (bx<<2) + (tid-4)];

        for (int t = 0; t <= 12; ++t){
            // -------- acquire step inputs --------
            if (t == 0){
                sH1[tid] = hch[tid];
            } else {
                if (t == 1) sH2[tid] = hch[256 + tid];
                if (tid < 64){
                    const int p = (t - 1) & 1;
                    const float* base = fdata + (size_t)(p*64 + tid)*32;
                    const float ft = (float)t;
                    if (t >= 2){
                        while (true){
                            PairU q[8];
                            #pragma unroll
                            for (int k = 0; k < 8; ++k) q[k].u = gload_ll(base + 2*k);
                            bool ok = true;
                            #pragma unroll
                            for (int k = 0; k < 8; ++k) ok &= (q[k].f[1] == ft);
                            if (__ballot(ok) == ALL64){
                                #pragma unroll
                                for (int k = 0; k < 4; ++k){
                                    sH1[4*tid + k] = q[k].f[0];
                                    sH2[4*tid + k] = q[4+k].f[0];
                                }
                                break;
                            }
                        }
                    } else { // t == 1: only layer-1 pairs exist
                        while (true){
                            PairU q[4];
                            #pragma unroll
                            for (int k = 0; k < 4; ++k) q[k].u = gload_ll(base + 2*k);
                            bool ok = true;
                            #pragma unroll
                            for (int k = 0; k < 4; ++k) ok &= (q[k].f[1] == ft);
                            if (__ballot(ok) == ALL64){
                                #pragma unroll
                                for (int k = 0; k < 4; ++k) sH1[4*tid + k] = q[k].f[0];
                                break;
                            }
                        }
                    }
                }
            }
            if (t < 12) sE[tid] = char_emb[x_char[t]*256 + tid];
            __syncthreads();

            // -------- gate dots --------
            float a1 = 0.f, a2 = 0.f;
            if (t < 12){
                const float* xp = sE  + lane16*16;
                const float* hp = sH1 + lane16*16;
                #pragma unroll
                for (int j = 0; j < 4; ++j) a1 += dot4(w1i[j], xp + 4*j) + dot4(w1h[j], hp + 4*j);
            }
            if (t >= 1){
                const float* xp = sH1 + lane16*16;
                const float* hp = sH2 + lane16*16;
                #pragma unroll
                for (int j = 0; j < 4; ++j) a2 += dot4(w2i[j], xp + 4*j) + dot4(w2h[j], hp + 4*j);
            }
            #pragma unroll
            for (int m = 8; m >= 1; m >>= 1){
                a1 += __shfl_xor(a1, m, 64);
                a2 += __shfl_xor(a2, m, 64);
            }
            if (lane16 == 0){
                if (t < 12) sg1[rg] = a1 + b1;
                if (t >= 1) sg2[rg] = a2 + b2;
            }
            __syncthreads();

            // -------- cell update + pair publish --------
            float* dst = fdata + (size_t)((t & 1)*64 + bx)*32;
            if (tid < 4){
                if (t < 12){
                    float gi = sigf(sg1[tid*4+0]);
                    float gf = sigf(sg1[tid*4+1]);
                    float gg = tanhf_(sg1[tid*4+2]);
                    float go = sigf(sg1[tid*4+3]);
                    float c = gf * c1r + gi * gg;
                    c1r = c;
                    float h = go * tanhf_(c);
                    h1fin = h;
                    PairU pr; pr.f[0] = h; pr.f[1] = (float)(t+1);
                    gstore_ll(dst + 2*tid, pr.u);
                }
            } else if (tid < 8){
                if (t >= 1){
                    int q = tid - 4;
                    float gi = sigf(sg2[q*4+0]);
                    float gf = sigf(sg2[q*4+1]);
                    float gg = tanhf_(sg2[q*4+2]);
                    float go = sigf(sg2[q*4+3]);
                    float c = gf * c2r + gi * gg;
                    c2r = c;
                    float h = go * tanhf_(c);
                    h2fin = h;
                    PairU pr; pr.f[0] = (t < 12) ? h : c;   // t==12 publishes c2 for mix
                    pr.f[1] = (float)(t+1);
                    gstore_ll(dst + 8 + 2*q, pr.u);
                }
            }
            __syncthreads();   // drains publish stores before any lane re-polls / next iter
        }

        // final char states from registers
        if (tid < 4){
            int uh = (bx << 2) + tid;
            out[52048 + uh] = h1fin;   // h_char_h layer0 (t==11)
            out[52560 + uh] = c1r;     // h_char_c layer0
        } else if (tid < 8){
            int uh = (bx << 2) + (tid - 4);
            out[52048 + 256 + uh] = h2fin;  // h_char_h layer1 (t==12)
            out[52560 + 256 + uh] = c2r;    // h_char_c layer1
        }

        // block 0 condenses "all char blocks done" into 64 spread lines
        if (bx == 0 && tid < 64){
            const float* base = fdata + (size_t)tid*32;   // parity 0, slots 4..7 hold {c2, 13}
            while (true){
                PairU q[4];
                #pragma unroll
                for (int k = 0; k < 4; ++k) q[k].u = gload_ll(base + 8 + 2*k);
                bool ok = true;
                #pragma unroll
                for (int k = 0; k < 4; ++k) ok &= (q[k].f[1] == 13.0f);
                if (__ballot(ok) == ALL64) break;
            }
            gstore_i(cdone + tid*32, 1);
        }

    } else if (bx < 192){
        // ================= gate + mix + word layer 0 =================
        __shared__ float sC2[256];
        __shared__ float sXCW[512];
        __shared__ float sMisc[8];
        const int vw = ((bx - 64) << 2) + wv;        // hidden unit 0..511
        float4 wi0[4], wi1[4], wh0[4], wh1[4]; float bs[4];
        #pragma unroll
        for (int gq = 0; gq < 4; ++gq){
            const size_t rf = (size_t)((gq << 9) + vw);
            const float4* pi = (const float4*)(wWih + rf*512) + lane*2;
            const float4* ph = (const float4*)(wWhh + rf*512) + lane*2;
            wi0[gq] = pi[0]; wi1[gq] = pi[1];
            wh0[gq] = ph[0]; wh1[gq] = ph[1];
            bs[gq] = wbih[rf] + wbhh[rf];
        }
        const float4* hv = (const float4*)(hwh) + lane*2;
        const float4 hva = hv[0], hvb = hv[1];
        const size_t wbase = (size_t)x_word[0] * 512;
        const float4* wep = (const float4*)(word_emb + wbase) + lane*2;
        const float4 wea = wep[0], web = wep[1];

        if (bx == 64){
            float p = g_w[2*tid]   * word_emb[wbase + 2*tid]
                    + g_w[2*tid+1] * word_emb[wbase + 2*tid+1];
            #pragma unroll
            for (int m = 32; m >= 1; m >>= 1) p += __shfl_xor(p, m, 64);
            if (lane == 0) sMisc[wv] = p;
            __syncthreads();
            if (tid == 0)
                gstore(ws + 3072, fmaxf(sMisc[0]+sMisc[1]+sMisc[2]+sMisc[3] + g_b[0], 0.0f));
        }

        // wait for char completion (spread cdone lines, <=2 pollers each)
        if (tid == 0){
            int* myline = cdone + ((bx - 64) & 63)*32;
            while (gload_i(myline) < 1) __builtin_amdgcn_s_sleep(4);
        }
        __syncthreads();
        // read c2 directly from the pairs (parity 0, slots 4..7)
        {
            PairU q;
            q.u = gload_ll(fdata + (size_t)(tid >> 2)*32 + 8 + 2*(tid & 3));
            sC2[tid] = q.f[0];
        }
        __syncthreads();

        // mix: xcw[vw] = cte[vw,:] . c2
        {
            float4 cv  = ((const float4*)(cte + (size_t)vw*256))[lane];
            float4 c2v = ((const float4*)sC2)[lane];
            float acc = dot44(cv, c2v);
            #pragma unroll
            for (int m = 32; m >= 1; m >>= 1) acc += __shfl_xor(acc, m, 64);
            if (lane == 0) gstore(ws + 1536 + vw, acc);
        }
        __syncthreads();                       // drain xcw stores
        if (tid == 0) gstore_i(w0f + (bx - 64), 1);
        if (tid < 64){
            while (true){
                unsigned long long v = gload_ll((const float*)(w0f + 2*tid));
                int lo = (int)(v & 0xffffffffu), hi = (int)(v >> 32);
                if (__ballot(lo >= 1 && hi >= 1) == ALL64) break;
            }
        }
        __syncthreads();
        sXCW[tid]       = gload(ws + 1536 + tid);
        sXCW[256 + tid] = gload(ws + 1536 + 256 + tid);
        if (tid == 0) sMisc[4] = gload(ws + 3072);
        __syncthreads();

        // word layer 0 (one unit per wave)
        {
            const float g  = sMisc[4];
            const float og = 1.0f - g;
            const float4 x0 = ((const float4*)sXCW)[lane*2];
            const float4 x1 = ((const float4*)sXCW)[lane*2 + 1];
            float4 xa, xb;
            xa.x = og*wea.x + g*x0.x; xa.y = og*wea.y + g*x0.y;
            xa.z = og*wea.z + g*x0.z; xa.w = og*wea.w + g*x0.w;
            xb.x = og*web.x + g*x1.x; xb.y = og*web.y + g*x1.y;
            xb.z = og*web.z + g*x1.z; xb.w = og*web.w + g*x1.w;
            float ac[4];
            #pragma unroll
            for (int gq = 0; gq < 4; ++gq){
                float a = dot44(wi0[gq], xa) + dot44(wi1[gq], xb)
                        + dot44(wh0[gq], hva) + dot44(wh1[gq], hvb);
                #pragma unroll
                for (int m = 32; m >= 1; m >>= 1) a += __shfl_xor(a, m, 64);
                ac[gq] = a;
            }
            if (lane == 0){
                float gi = sigf(ac[0] + bs[0]);
                float gf = sigf(ac[1] + bs[1]);
                float gg = tanhf_(ac[2] + bs[2]);
                float go = sigf(ac[3] + bs[3]);
                float c = gf * hwc[vw] + gi * gg;
                float h = go * tanhf_(c);
                gstore(ws + 2048 + vw, h);
                out[50000 + vw] = h;
                out[51024 + vw] = c;
            }
        }
        __syncthreads();                       // drain hw1 stores
        if (tid == 0) gstore_i(w0f + (bx - 64), 2);

    } else {
        // ================= word layer 1 =================
        __shared__ float sX1[512];
        const int vw = ((bx - 192) << 2) + wv;       // hidden unit 0..511
        float4 wi0[4], wi1[4], wh0[4], wh1[4]; float bs[4];
        #pragma unroll
        for (int gq = 0; gq < 4; ++gq){
            const size_t rf = (size_t)(2048 + (gq << 9) + vw);
            const float4* pi = (const float4*)(wWih + rf*512) + lane*2;
            const float4* ph = (const float4*)(wWhh + rf*512) + lane*2;
            wi0[gq] = pi[0]; wi1[gq] = pi[1];
            wh0[gq] = ph[0]; wh1[gq] = ph[1];
            bs[gq] = wbih[rf] + wbhh[rf];
        }
        const float4* hv = (const float4*)(hwh + 512) + lane*2;
        const float4 hva = hv[0], hvb = hv[1];

        if (tid < 64){
            while (true){
                unsigned long long v = gload_ll((const float*)(w0f + 2*tid));
                int lo = (int)(v & 0xffffffffu), hi = (int)(v >> 32);
                if (__ballot(lo >= 2 && hi >= 2) == ALL64) break;
                __builtin_amdgcn_s_sleep(2);
            }
        }
        __syncthreads();
        sX1[tid]       = gload(ws + 2048 + tid);
        sX1[256 + tid] = gload(ws + 2048 + 256 + tid);
        __syncthreads();
        {
            const float4 xa = ((const float4*)sX1)[lane*2];
            const float4 xb = ((const float4*)sX1)[lane*2 + 1];
            float ac[4];
            #pragma unroll
            for (int gq = 0; gq < 4; ++gq){
                float a = dot44(wi0[gq], xa) + dot44(wi1[gq], xb)
                        + dot44(wh0[gq], hva) + dot44(wh1[gq], hvb);
                #pragma unroll
                for (int m = 32; m >= 1; m >>= 1) a += __shfl_xor(a, m, 64);
                ac[gq] = a;
            }
            if (lane == 0){
                float gi = sigf(ac[0] + bs[0]);
                float gf = sigf(ac[1] + bs[1]);
                float gg = tanhf_(ac[2] + bs[2]);
                float go = sigf(ac[3] + bs[3]);
                float c = gf * hwc[512 + vw] + gi * gg;
                float h = go * tanhf_(c);
                gstore(ws + 2560 + vw, h);
                out[50000 + 512 + vw] = h;
                out[51024 + 512 + vw] = c;
            }
        }
        __syncthreads();                       // drain hw2 stores
        if (tid == 0) gstore_i(w1f + (bx - 192), 1);
    }

    // ================= decoder (all 320 blocks, 1280 waves, HBM-streaming) =================
    if (tid < 64){
        while (true){
            unsigned long long v = gload_ll((const float*)(w1f + 2*tid));
            int lo = (int)(v & 0xffffffffu), hi = (int)(v >> 32);
            if (__ballot(lo >= 1 && hi >= 1) == ALL64) break;
            __builtin_amdgcn_s_sleep(8);
        }
    }
    __syncthreads();
    sHW[tid]       = gload(ws + 2560 + tid);
    sHW[256 + tid] = gload(ws + 2560 + 256 + tid);
    __syncthreads();
    {
        // 2 rows per wave per iteration; 32 lanes per row; fully coalesced 512B
        // segments per instruction; h preloaded into registers (no LDS in loop).
        const int wid  = (bx << 2) + wv;          // 0..1279
        const int cc   = lane & 31;
        const int half = lane >> 5;
        float4 hq[4];
        const float4* sf4 = (const float4*)sHW;
        #pragma unroll
        for (int j = 0; j < 4; ++j) hq[j] = sf4[cc + j*32];

        for (int r0 = wid*2; r0 < 50000; r0 += 2560){
            const int r = r0 + half;
            const float4* wp = (const float4*)(dec_W + (size_t)r*512) + cc;
            float4 wb[4];
            #pragma unroll
            for (int j = 0; j < 4; ++j) wb[j] = wp[j*32];
            float acc = 0.f;
            #pragma unroll
            for (int j = 0; j < 4; ++j) acc += dot44(wb[j], hq[j]);
            acc += __shfl_xor(acc, 1, 64);
            acc += __shfl_xor(acc, 2, 64);
            acc += __shfl_xor(acc, 4, 64);
            acc += __shfl_xor(acc, 8, 64);
            acc += __shfl_xor(acc, 16, 64);
            if (cc == 0) out[r] = acc + dec_b[r];
        }
    }
}

extern "C" void kernel_launch(void* const* d_in, const int* in_sizes, int n_in,
                              void* d_out, int out_size, void* d_ws, size_t ws_size,
                              hipStream_t stream)
{
    const int*   x_word   = (const int*)d_in[0];
    const int*   x_char   = (const int*)d_in[1];
    const float* hwh      = (const float*)d_in[2];
    const float* hwc      = (const float*)d_in[3];
    const float* hch      = (const float*)d_in[4];
    const float* hcc      = (const float*)d_in[5];
    const float* word_emb = (const float*)d_in[6];
    const float* wWih     = (const float*)d_in[7];
    const float* wWhh     = (const float*)d_in[8];
    const float* wbih     = (const float*)d_in[9];
    const float* wbhh     = (const float*)d_in[10];
    const float* dec_W    = (const float*)d_in[11];
    const float* dec_b    = (const float*)d_in[12];
    const float* char_emb = (const float*)d_in[13];
    const float* cWih     = (const float*)d_in[14];
    const float* cWhh     = (const float*)d_in[15];
    const float* cbih     = (const float*)d_in[16];
    const float* cbhh     = (const float*)d_in[17];
    const float* cte      = (const float*)d_in[18];
    const float* g_w      = (const float*)d_in[19];
    const float* g_b      = (const float*)d_in[20];

    float* ws  = (float*)d_ws;
    float* out = (float*)d_out;

    // zero flag + pair-exchange region (ws bytes 16384..49151)
    hipMemsetAsync((void*)((char*)d_ws + 16384), 0, 32768, stream);

    hipLaunchKernelGGL(k_fused, dim3(320), dim3(256), 0, stream,
        x_word, x_char, hwh, hwc, hch, hcc, word_emb,
        wWih, wWhh, wbih, wbhh, dec_W, dec_b,
        char_emb, cWih, cWhh, cbih, cbhh, cte, g_w, g_b,
        ws, out);
}

// Round 6
// 287.032 us; speedup vs baseline: 2.0727x; 1.0432x over previous
//
#include <hip/hip_runtime.h>
#include <stdint.h>

// GatedLSTM — single persistent-grid fused kernel, round 6.
// All cross-block sync is TAG-IN-DATA {value, tag} 8B pairs, replicated to spread
// read fan-in; long waits are single-lane sentinel polls (1 poller/line) followed
// by ballot-verified bulk reads. No flag arrays, no RMW, no mass polling.
// Char exchange: LDS-bounce publish to 4 replicas; consumers use 16B sc0/sc1 asm
// loads (4/lane). Embeddings for all 12 steps pre-staged in LDS.
//
// ws float layout (memset 69888 B per launch):
//   fdata  [0 .. 8192)     ((p*64+b)*4+rep)*16 : char h pairs, tag t+1
//   c2rep  [8192 .. 9216)  2 reps x 256 pairs, tag 13
//   xcwrep [9216 .. 11264) 2 reps x 512 pairs, tag 1
//   hw1rep [11264 .. 13312) 2 reps x 512 pairs, tag 1
//   hw2rep [13312 .. 17408) 4 reps x 512 pairs, tag 1
//   grep   [17408 .. 17472) 2 reps (stride 32), tag 1

#define SCOPE_AGT __HIP_MEMORY_SCOPE_AGENT
#define ALL64 0xFFFFFFFFFFFFFFFFull

static __device__ __forceinline__ float dot4(float4 w, const float* p){
    return w.x*p[0] + w.y*p[1] + w.z*p[2] + w.w*p[3];
}
static __device__ __forceinline__ float dot44(float4 a, float4 b){
    return a.x*b.x + a.y*b.y + a.z*b.z + a.w*b.w;
}
static __device__ __forceinline__ float sigf(float x){ return 1.0f / (1.0f + __expf(-x)); }
static __device__ __forceinline__ float tanhf_(float x){
    x = fminf(fmaxf(x, -15.0f), 15.0f);
    float e = __expf(2.0f * x);
    return (e - 1.0f) / (e + 1.0f);
}

static __device__ __forceinline__ void gstore_ll(float* p, unsigned long long v){
    __hip_atomic_store((unsigned long long*)p, v, __ATOMIC_RELAXED, SCOPE_AGT);
}
static __device__ __forceinline__ unsigned long long gload_ll(const float* p){
    return __hip_atomic_load((const unsigned long long*)p, __ATOMIC_RELAXED, SCOPE_AGT);
}

union PairU { unsigned long long u; float f[2]; };

// 16B / 32B / 64B L2-bypassing loads (read at the LLC coherence point).
static __device__ __forceinline__ float4 sc_load16(const float* p){
    float4 r;
    asm volatile("global_load_dwordx4 %0, %1, off sc0 sc1\n\t"
                 "s_waitcnt vmcnt(0)"
                 : "=&v"(r) : "v"(p) : "memory");
    return r;
}
static __device__ __forceinline__ void sc_load32(const float* p, float4& a, float4& b){
    asm volatile("global_load_dwordx4 %0, %2, off sc0 sc1\n\t"
                 "global_load_dwordx4 %1, %2, off offset:16 sc0 sc1\n\t"
                 "s_waitcnt vmcnt(0)"
                 : "=&v"(a), "=&v"(b) : "v"(p) : "memory");
}
static __device__ __forceinline__ void sc_load64(const float* p, float4& a, float4& b,
                                                 float4& c, float4& d){
    asm volatile("global_load_dwordx4 %0, %4, off sc0 sc1\n\t"
                 "global_load_dwordx4 %1, %4, off offset:16 sc0 sc1\n\t"
                 "global_load_dwordx4 %2, %4, off offset:32 sc0 sc1\n\t"
                 "global_load_dwordx4 %3, %4, off offset:48 sc0 sc1\n\t"
                 "s_waitcnt vmcnt(0)"
                 : "=&v"(a), "=&v"(b), "=&v"(c), "=&v"(d) : "v"(p) : "memory");
}

#define WS_C2   8192
#define WS_XCW  9216
#define WS_HW1  11264
#define WS_HW2  13312
#define WS_G    17408

__global__ __launch_bounds__(256, 2) void k_fused(
    const int* __restrict__ x_word, const int* __restrict__ x_char,
    const float* __restrict__ hwh, const float* __restrict__ hwc,
    const float* __restrict__ hch, const float* __restrict__ hcc,
    const float* __restrict__ word_emb,
    const float* __restrict__ wWih, const float* __restrict__ wWhh,
    const float* __restrict__ wbih, const float* __restrict__ wbhh,
    const float* __restrict__ dec_W, const float* __restrict__ dec_b,
    const float* __restrict__ char_emb,
    const float* __restrict__ cWih, const float* __restrict__ cWhh,
    const float* __restrict__ cbih, const float* __restrict__ cbhh,
    const float* __restrict__ cte,
    const float* __restrict__ g_w, const float* __restrict__ g_b,
    float* __restrict__ ws, float* __restrict__ out)
{
    const int tid  = threadIdx.x;
    const int bx   = blockIdx.x;
    const int lane = tid & 63;
    const int wv   = tid >> 6;

    __shared__ float sHW[512];      // decoder h (all roles)

    if (bx < 64){
        // ================= char LSTM (13 steps) =================
        __shared__ float sH1[256], sH2[256], sg1[16], sg2[16], sPub[8];
        __shared__ float sEall[12][256];
        __shared__ int   sXC[12];

        const int rg = tid >> 4, lane16 = tid & 15;
        const int gate = rg & 3, uu = rg >> 2;
        const int u = (bx << 2) + uu;
        const int row = (gate << 8) + u, row2 = 1024 + row;

        float4 w1i[4], w1h[4], w2i[4], w2h[4];
        {
            const float4* p1i = (const float4*)(cWih + (size_t)row  * 256) + lane16 * 4;
            const float4* p1h = (const float4*)(cWhh + (size_t)row  * 256) + lane16 * 4;
            const float4* p2i = (const float4*)(cWih + (size_t)row2 * 256) + lane16 * 4;
            const float4* p2h = (const float4*)(cWhh + (size_t)row2 * 256) + lane16 * 4;
            #pragma unroll
            for (int j = 0; j < 4; ++j){ w1i[j]=p1i[j]; w1h[j]=p1h[j]; w2i[j]=p2i[j]; w2h[j]=p2h[j]; }
        }
        const float b1 = cbih[row]  + cbhh[row];
        const float b2 = cbih[row2] + cbhh[row2];

        // pre-stage all 12 embeddings (removes serial x_char->char_emb chain)
        if (tid < 12) sXC[tid] = x_char[tid];
        __syncthreads();
        for (int s = 0; s < 12; ++s) sEall[s][tid] = char_emb[sXC[s]*256 + tid];

        float c1r = 0.f, c2r = 0.f, h1fin = 0.f, h2fin = 0.f;
        if (tid < 4)      c1r = hcc[(bx<<2) + tid];
        else if (tid < 8) c2r = hcc[256 + (bx<<2) + (tid-4)];

        for (int t = 0; t <= 12; ++t){
            // -------- acquire step inputs --------
            if (t == 0){
                sH1[tid] = hch[tid];
            } else {
                if (t == 1) sH2[tid] = hch[256 + tid];
                if (tid < 64){
                    const int p = (t - 1) & 1;
                    const float* base = ws + ((size_t)((p*64 + tid)*4 + (bx & 3)) * 16);
                    const float ft = (float)t;
                    if (t >= 2){
                        while (true){
                            float4 a,b,c,d;
                            sc_load64(base, a, b, c, d);
                            bool ok = (a.y==ft)&&(a.w==ft)&&(b.y==ft)&&(b.w==ft)
                                   && (c.y==ft)&&(c.w==ft)&&(d.y==ft)&&(d.w==ft);
                            if (__ballot(ok) == ALL64){
                                sH1[4*tid+0]=a.x; sH1[4*tid+1]=a.z; sH1[4*tid+2]=b.x; sH1[4*tid+3]=b.z;
                                sH2[4*tid+0]=c.x; sH2[4*tid+1]=c.z; sH2[4*tid+2]=d.x; sH2[4*tid+3]=d.z;
                                break;
                            }
                        }
                    } else {
                        while (true){
                            float4 a,b;
                            sc_load32(base, a, b);
                            bool ok = (a.y==ft)&&(a.w==ft)&&(b.y==ft)&&(b.w==ft);
                            if (__ballot(ok) == ALL64){
                                sH1[4*tid+0]=a.x; sH1[4*tid+1]=a.z; sH1[4*tid+2]=b.x; sH1[4*tid+3]=b.z;
                                break;
                            }
                        }
                    }
                }
            }
            __syncthreads();

            // -------- gate dots --------
            float a1 = 0.f, a2 = 0.f;
            if (t < 12){
                const float* xp = &sEall[t][0] + lane16*16;
                const float* hp = sH1 + lane16*16;
                #pragma unroll
                for (int j = 0; j < 4; ++j) a1 += dot4(w1i[j], xp + 4*j) + dot4(w1h[j], hp + 4*j);
            }
            if (t >= 1){
                const float* xp = sH1 + lane16*16;
                const float* hp = sH2 + lane16*16;
                #pragma unroll
                for (int j = 0; j < 4; ++j) a2 += dot4(w2i[j], xp + 4*j) + dot4(w2h[j], hp + 4*j);
            }
            #pragma unroll
            for (int m = 8; m >= 1; m >>= 1){
                a1 += __shfl_xor(a1, m, 64);
                a2 += __shfl_xor(a2, m, 64);
            }
            if (lane16 == 0){
                if (t < 12) sg1[rg] = a1 + b1;
                if (t >= 1) sg2[rg] = a2 + b2;
            }
            __syncthreads();

            // -------- cell update (into LDS bounce) --------
            if (tid < 4){
                if (t < 12){
                    float gi = sigf(sg1[tid*4+0]);
                    float gf = sigf(sg1[tid*4+1]);
                    float gg = tanhf_(sg1[tid*4+2]);
                    float go = sigf(sg1[tid*4+3]);
                    float c = gf * c1r + gi * gg;
                    c1r = c;
                    float h = go * tanhf_(c);
                    h1fin = h;
                    sPub[tid] = h;
                }
            } else if (tid < 8){
                if (t >= 1){
                    int q = tid - 4;
                    float gi = sigf(sg2[q*4+0]);
                    float gf = sigf(sg2[q*4+1]);
                    float gg = tanhf_(sg2[q*4+2]);
                    float go = sigf(sg2[q*4+3]);
                    float c = gf * c2r + gi * gg;
                    c2r = c;
                    float h = go * tanhf_(c);
                    h2fin = h;
                    sPub[tid] = (t < 12) ? h : c;   // t==12 publishes c2
                }
            }
            __syncthreads();

            // -------- replicated publish (one store per lane) --------
            if (t < 12){
                if (tid < 32){
                    const int rep = tid >> 3, k = tid & 7;
                    const bool valid = (k < 4) ? true : (t >= 1);
                    if (valid){
                        PairU pr; pr.f[0] = sPub[k]; pr.f[1] = (float)(t+1);
                        gstore_ll(ws + ((size_t)(((t&1)*64 + bx)*4 + rep) * 16) + 2*k, pr.u);
                    }
                }
            } else {
                if (tid < 8){
                    const int rep = tid >> 2, uq = tid & 3;
                    PairU pr; pr.f[0] = sPub[4+uq]; pr.f[1] = 13.0f;
                    gstore_ll(ws + WS_C2 + rep*512 + ((bx<<2)+uq)*2, pr.u);
                }
            }
        }

        // final char states from registers
        if (tid < 4){
            int uh = (bx << 2) + tid;
            out[52048 + uh] = h1fin;
            out[52560 + uh] = c1r;
        } else if (tid < 8){
            int uh = (bx << 2) + (tid - 4);
            out[52048 + 256 + uh] = h2fin;
            out[52560 + 256 + uh] = c2r;
        }

    } else if (bx < 192){
        // ================= gate + mix + word layer 0 =================
        __shared__ float sC2[256], sXCW[512], sAcc[8], sG[4], sH0[4];
        const int mb = bx - 64;
        const int vwb = mb << 2;
        const int vw = vwb + wv;
        float4 wi0[4], wi1[4], wh0[4], wh1[4]; float bs[4];
        #pragma unroll
        for (int gq = 0; gq < 4; ++gq){
            const size_t rf = (size_t)((gq << 9) + vw);
            const float4* pi = (const float4*)(wWih + rf*512) + lane*2;
            const float4* ph = (const float4*)(wWhh + rf*512) + lane*2;
            wi0[gq] = pi[0]; wi1[gq] = pi[1];
            wh0[gq] = ph[0]; wh1[gq] = ph[1];
            bs[gq] = wbih[rf] + wbhh[rf];
        }
        const float4* hv = (const float4*)(hwh) + lane*2;
        const float4 hva = hv[0], hvb = hv[1];
        const size_t wbase = (size_t)x_word[0] * 512;
        const float4* wep = (const float4*)(word_emb + wbase) + lane*2;
        const float4 wea = wep[0], web = wep[1];

        if (bx == 64){
            float p = g_w[2*tid]   * word_emb[wbase + 2*tid]
                    + g_w[2*tid+1] * word_emb[wbase + 2*tid+1];
            #pragma unroll
            for (int m = 32; m >= 1; m >>= 1) p += __shfl_xor(p, m, 64);
            if (lane == 0) sAcc[wv] = p;
            __syncthreads();
            if (tid == 0){
                float gg = fmaxf(sAcc[0]+sAcc[1]+sAcc[2]+sAcc[3] + g_b[0], 0.0f);
                PairU pr; pr.f[0] = gg; pr.f[1] = 1.0f;
                gstore_ll(ws + WS_G, pr.u);
                gstore_ll(ws + WS_G + 32, pr.u);
            }
            __syncthreads();
        }

        // sentinel wait for c2 (1 poller per block, spread lines)
        if (tid == 0){
            const float* sp = ws + WS_C2 + (bx & 1)*512 + ((bx*37) & 255)*2;
            while (true){
                PairU q; q.u = gload_ll(sp);
                if (q.f[1] == 13.0f) break;
                __builtin_amdgcn_s_sleep(2);
            }
        }
        __syncthreads();
        // bulk verified read of c2
        {
            const float* cb = ws + WS_C2 + (bx & 1)*512;
            while (true){
                PairU q; q.u = gload_ll(cb + tid*2);
                if (__ballot(q.f[1] == 13.0f) == ALL64){ sC2[tid] = q.f[0]; break; }
            }
        }
        __syncthreads();

        // mix: xcw[vw] = cte[vw,:] . c2
        {
            float4 cv  = ((const float4*)(cte + (size_t)vw*256))[lane];
            float4 c2v = ((const float4*)sC2)[lane];
            float acc = dot44(cv, c2v);
            #pragma unroll
            for (int m = 32; m >= 1; m >>= 1) acc += __shfl_xor(acc, m, 64);
            if (lane == 0) sAcc[wv] = acc;
        }
        __syncthreads();
        if (tid < 8){
            const int rep = tid >> 2, uq = tid & 3;
            PairU pr; pr.f[0] = sAcc[uq]; pr.f[1] = 1.0f;
            gstore_ll(ws + WS_XCW + rep*1024 + (vwb+uq)*2, pr.u);
        }
        if (tid == 1){
            while (true){
                PairU q; q.u = gload_ll(ws + WS_G + (bx & 1)*32);
                if (q.f[1] == 1.0f){ sG[0] = q.f[0]; break; }
            }
        }
        // bulk verified read of xcw (2 pairs / thread)
        {
            const float* xb = ws + WS_XCW + (bx & 1)*1024;
            while (true){
                float4 v4 = sc_load16(xb + 4*tid);
                if (__ballot(v4.y == 1.0f && v4.w == 1.0f) == ALL64){
                    sXCW[2*tid] = v4.x; sXCW[2*tid+1] = v4.z; break;
                }
            }
        }
        __syncthreads();

        // word layer 0 (one unit per wave)
        {
            const float g  = sG[0];
            const float og = 1.0f - g;
            const float4 x0 = ((const float4*)sXCW)[lane*2];
            const float4 x1 = ((const float4*)sXCW)[lane*2 + 1];
            float4 xa, xb;
            xa.x = og*wea.x + g*x0.x; xa.y = og*wea.y + g*x0.y;
            xa.z = og*wea.z + g*x0.z; xa.w = og*wea.w + g*x0.w;
            xb.x = og*web.x + g*x1.x; xb.y = og*web.y + g*x1.y;
            xb.z = og*web.z + g*x1.z; xb.w = og*web.w + g*x1.w;
            float ac[4];
            #pragma unroll
            for (int gq = 0; gq < 4; ++gq){
                float a = dot44(wi0[gq], xa) + dot44(wi1[gq], xb)
                        + dot44(wh0[gq], hva) + dot44(wh1[gq], hvb);
                #pragma unroll
                for (int m = 32; m >= 1; m >>= 1) a += __shfl_xor(a, m, 64);
                ac[gq] = a;
            }
            if (lane == 0){
                float gi = sigf(ac[0] + bs[0]);
                float gf = sigf(ac[1] + bs[1]);
                float gg = tanhf_(ac[2] + bs[2]);
                float go = sigf(ac[3] + bs[3]);
                float c = gf * hwc[vw] + gi * gg;
                float h = go * tanhf_(c);
                sH0[wv] = h;
                out[50000 + vw] = h;
                out[51024 + vw] = c;
            }
        }
        __syncthreads();
        if (tid < 8){
            const int rep = tid >> 2, uq = tid & 3;
            PairU pr; pr.f[0] = sH0[uq]; pr.f[1] = 1.0f;
            gstore_ll(ws + WS_HW1 + rep*1024 + (vwb+uq)*2, pr.u);
        }

    } else {
        // ================= word layer 1 =================
        __shared__ float sX1[512], sH1v[4];
        const int mb = bx - 192;
        const int vwb = mb << 2;
        const int vw = vwb + wv;
        float4 wi0[4], wi1[4], wh0[4], wh1[4]; float bs[4];
        #pragma unroll
        for (int gq = 0; gq < 4; ++gq){
            const size_t rf = (size_t)(2048 + (gq << 9) + vw);
            const float4* pi = (const float4*)(wWih + rf*512) + lane*2;
            const float4* ph = (const float4*)(wWhh + rf*512) + lane*2;
            wi0[gq] = pi[0]; wi1[gq] = pi[1];
            wh0[gq] = ph[0]; wh1[gq] = ph[1];
            bs[gq] = wbih[rf] + wbhh[rf];
        }
        const float4* hv = (const float4*)(hwh + 512) + lane*2;
        const float4 hva = hv[0], hvb = hv[1];

        // sentinel wait for hw1 (1 poller per block, spread lines)
        if (tid == 0){
            const float* sp = ws + WS_HW1 + (bx & 1)*1024 + ((bx*37) & 511)*2;
            while (true){
                PairU q; q.u = gload_ll(sp);
                if (q.f[1] == 1.0f) break;
                __builtin_amdgcn_s_sleep(4);
            }
        }
        __syncthreads();
        {
            const float* xb = ws + WS_HW1 + (bx & 1)*1024;
            while (true){
                float4 v4 = sc_load16(xb + 4*tid);
                if (__ballot(v4.y == 1.0f && v4.w == 1.0f) == ALL64){
                    sX1[2*tid] = v4.x; sX1[2*tid+1] = v4.z; break;
                }
            }
        }
        __syncthreads();
        {
            const float4 xa = ((const float4*)sX1)[lane*2];
            const float4 xb = ((const float4*)sX1)[lane*2 + 1];
            float ac[4];
            #pragma unroll
            for (int gq = 0; gq < 4; ++gq){
                float a = dot44(wi0[gq], xa) + dot44(wi1[gq], xb)
                        + dot44(wh0[gq], hva) + dot44(wh1[gq], hvb);
                #pragma unroll
                for (int m = 32; m >= 1; m >>= 1) a += __shfl_xor(a, m, 64);
                ac[gq] = a;
            }
            if (lane == 0){
                float gi = sigf(ac[0] + bs[0]);
                float gf = sigf(ac[1] + bs[1]);
                float gg = tanhf_(ac[2] + bs[2]);
                float go = sigf(ac[3] + bs[3]);
                float c = gf * hwc[512 + vw] + gi * gg;
                float h = go * tanhf_(c);
                sH1v[wv] = h;
                out[50000 + 512 + vw] = h;
                out[51024 + 512 + vw] = c;
            }
        }
        __syncthreads();
        if (tid < 16){
            const int rep = tid >> 2, uq = tid & 3;
            PairU pr; pr.f[0] = sH1v[uq]; pr.f[1] = 1.0f;
            gstore_ll(ws + WS_HW2 + rep*1024 + (vwb+uq)*2, pr.u);
        }
    }

    // ================= decoder (all 320 blocks) =================
    // sentinel wait for hw2 (1 poller per block, spread lines)
    if (tid == 0){
        const float* sp = ws + WS_HW2 + (bx & 3)*1024 + ((bx*37) & 511)*2;
        while (true){
            PairU q; q.u = gload_ll(sp);
            if (q.f[1] == 1.0f) break;
            __builtin_amdgcn_s_sleep(4);
        }
    }
    __syncthreads();
    {
        const float* hb = ws + WS_HW2 + (bx & 3)*1024;
        while (true){
            float4 v4 = sc_load16(hb + 4*tid);
            if (__ballot(v4.y == 1.0f && v4.w == 1.0f) == ALL64){
                sHW[2*tid] = v4.x; sHW[2*tid+1] = v4.z; break;
            }
        }
    }
    __syncthreads();
    {
        // 2 rows/wave/iter; 32 lanes/row; coalesced 512B segments; h in regs.
        const int wid  = (bx << 2) + wv;          // 0..1279
        const int cc   = lane & 31;
        const int half = lane >> 5;
        float4 hq[4];
        const float4* sf4 = (const float4*)sHW;
        #pragma unroll
        for (int j = 0; j < 4; ++j) hq[j] = sf4[cc + j*32];

        for (int r0 = wid*2; r0 < 50000; r0 += 2560){
            const int r = r0 + half;
            const float4* wp = (const float4*)(dec_W + (size_t)r*512) + cc;
            float4 wb[4];
            #pragma unroll
            for (int j = 0; j < 4; ++j) wb[j] = wp[j*32];
            float acc = 0.f;
            #pragma unroll
            for (int j = 0; j < 4; ++j) acc += dot44(wb[j], hq[j]);
            acc += __shfl_xor(acc, 1, 64);
            acc += __shfl_xor(acc, 2, 64);
            acc += __shfl_xor(acc, 4, 64);
            acc += __shfl_xor(acc, 8, 64);
            acc += __shfl_xor(acc, 16, 64);
            if (cc == 0) out[r] = acc + dec_b[r];
        }
    }
}

extern "C" void kernel_launch(void* const* d_in, const int* in_sizes, int n_in,
                              void* d_out, int out_size, void* d_ws, size_t ws_size,
                              hipStream_t stream)
{
    const int*   x_word   = (const int*)d_in[0];
    const int*   x_char   = (const int*)d_in[1];
    const float* hwh      = (const float*)d_in[2];
    const float* hwc      = (const float*)d_in[3];
    const float* hch      = (const float*)d_in[4];
    const float* hcc      = (const float*)d_in[5];
    const float* word_emb = (const float*)d_in[6];
    const float* wWih     = (const float*)d_in[7];
    const float* wWhh     = (const float*)d_in[8];
    const float* wbih     = (const float*)d_in[9];
    const float* wbhh     = (const float*)d_in[10];
    const float* dec_W    = (const float*)d_in[11];
    const float* dec_b    = (const float*)d_in[12];
    const float* char_emb = (const float*)d_in[13];
    const float* cWih     = (const float*)d_in[14];
    const float* cWhh     = (const float*)d_in[15];
    const float* cbih     = (const float*)d_in[16];
    const float* cbhh     = (const float*)d_in[17];
    const float* cte      = (const float*)d_in[18];
    const float* g_w      = (const float*)d_in[19];
    const float* g_b      = (const float*)d_in[20];

    float* ws  = (float*)d_ws;
    float* out = (float*)d_out;

    // zero the pair-exchange region (17472 floats)
    hipMemsetAsync(d_ws, 0, 69888, stream);

    hipLaunchKernelGGL(k_fused, dim3(320), dim3(256), 0, stream,
        x_word, x_char, hwh, hwc, hch, hcc, word_emb,
        wWih, wWhh, wbih, wbhh, dec_W, dec_b,
        char_emb, cWih, cWhh, cbih, cbhh, cte, g_w, g_b,
        ws, out);
}